// Round 12
// baseline (369.634 us; speedup 1.0000x reference)
//
#include <hip/hip_runtime.h>

// B=2, T=2048, C=1024, H=16, D=64. Inputs fp32, OUTPUT fp32.
// Round 24 (post-mortem R23: interleaved dual-phase fixed locality but VGPR
// 52->108 killed occupancy and loop-length imbalance survived. Best flash =
// R21 geometry, 54.4us; residual = CU drain with no backfill capacity):
//  - flash_k: R21 structure (64-row Q tiles, grid (32,32), 256 thr, 1 strip/
//    wave) + V LDS staging DROPPED — PV's av frags read directly from global
//    vt (b64/lane; 256KB chip-wide working set per kt = L2-resident; issued
//    ~300cy before PV consumes). LDS 36.9->18.4KB => 8 blocks/CU capacity,
//    launch_bounds(256,8) caps VGPR at 64 (R21 was 52; vr prefetch regs
//    freed). Short blocks retire -> fresh blocks BACKFILL -> drain becomes
//    sliding window.
//  - prep_k / qkv_rope_k / proj_k unchanged.
// MFMA 16x16x32_bf16 layouts (HW-verified): A: m=lane&15,k=quad*8+j;
// B: k=quad*8+j,n=lane&15; C/D: col=lane&15,row=quad*4+reg.
// MFMA 16x16x16_bf16 (HW-verified R17): A: m=lane&15,k=quad*4+j;
// B: k=quad*4+j,n=lane&15; C/D: col=lane&15,row=quad*4+reg.

typedef unsigned short u16;
typedef u16 u16x4 __attribute__((ext_vector_type(4)));
typedef u16 u16x8 __attribute__((ext_vector_type(8)));
typedef short s16x4 __attribute__((ext_vector_type(4)));
typedef short s16x8 __attribute__((ext_vector_type(8)));
typedef float f32x4 __attribute__((ext_vector_type(4)));

#define T_SEQ 2048
#define C_EMB 1024
#define NH 16
#define HD 64

#define MFMA16(a, b, c) __builtin_amdgcn_mfma_f32_16x16x32_bf16(a, b, c, 0, 0, 0)

__device__ __forceinline__ f32x4 MFMA16K16(s16x4 a, s16x4 b, f32x4 c) {
#if __has_builtin(__builtin_amdgcn_mfma_f32_16x16x16bf16_1k)
    return __builtin_amdgcn_mfma_f32_16x16x16bf16_1k(a, b, c, 0, 0, 0);
#else
    asm("v_mfma_f32_16x16x16_bf16 %0, %1, %2, %0" : "+v"(c) : "v"(a), "v"(b));
    return c;
#endif
}

__device__ __forceinline__ u16 f2bf(float f) {
    union { float f; unsigned int i; } x; x.f = f;
    unsigned int r = x.i + 0x7fffu + ((x.i >> 16) & 1u);
    return (u16)(r >> 16);
}
__device__ __forceinline__ u16x4 pack4(f32x4 v) {
    u16x4 o;
#pragma unroll
    for (int j = 0; j < 4; ++j) o[j] = f2bf(v[j]);
    return o;
}
// hot-loop pack: HW packed convert (RNE), 2 instr per 4 values -> s16x4 frag
__device__ __forceinline__ s16x4 pack4cvt_s(f32x4 v) {
    union { s16x4 h; unsigned int w[2]; } u;
    asm("v_cvt_pk_bf16_f32 %0, %1, %2" : "=v"(u.w[0]) : "v"(v[0]), "v"(v[1]));
    asm("v_cvt_pk_bf16_f32 %0, %1, %2" : "=v"(u.w[1]) : "v"(v[2]), "v"(v[3]));
    return u.h;
}
// async global->LDS, 16B per lane (dest must be wave-uniform base + lane*16)
__device__ __forceinline__ void gload16(const void* g, void* l) {
    __builtin_amdgcn_global_load_lds(
        (const __attribute__((address_space(1))) unsigned int*)g,
        (__attribute__((address_space(3))) unsigned int*)l, 16, 0, 0);
}

// ---------------- k0: merged prep (3x fp32->bf16 conv + rope tables) -------
// grid 4352: [0,2048) conv x; [2048,3584) conv Wa; [3584,4096) conv Wp;
// [4096,4352) rope tables. All sections exact-sized (no bounds checks).
__global__ __launch_bounds__(256) void prep_k(const float* __restrict__ x, const float* __restrict__ Wa,
                                              const float* __restrict__ Wp,
                                              u16* __restrict__ xb, u16* __restrict__ Wab,
                                              u16* __restrict__ Wpb, float2* __restrict__ tab) {
    int bid = blockIdx.x, tid = threadIdx.x;
    if (bid < 4096) {
        const float* src;
        u16* dst;
        int i;
        if (bid < 2048)      { src = x;  dst = xb;  i = bid * 256 + tid; }
        else if (bid < 3584) { src = Wa; dst = Wab; i = (bid - 2048) * 256 + tid; }
        else                 { src = Wp; dst = Wpb; i = (bid - 3584) * 256 + tid; }
        f32x4 a = ((const f32x4*)src)[i * 2];
        f32x4 b = ((const f32x4*)src)[i * 2 + 1];
        u16x8 o;
#pragma unroll
        for (int j = 0; j < 4; ++j) o[j] = f2bf(a[j]);
#pragma unroll
        for (int j = 0; j < 4; ++j) o[4 + j] = f2bf(b[j]);
        ((u16x8*)dst)[i] = o;
    } else {
        int idx = (bid - 4096) * 256 + tid;   // 65536 = T*32
        int t = idx >> 5, j = idx & 31;
        float inv = __builtin_exp2f(-0.41524101186092f * (float)j);  // 10000^(-j/32)
        float s_, c_;
        sincosf((float)t * inv, &s_, &c_);
        tab[idx] = make_float2(c_, s_);
    }
}

// ---------------- k1: QKV GEMM + RoPE (gload_lds, BK=32, 3-deep pipeline) --
// grid (24, 32): n0 = bx*128 (0..3071), m0 = by*128 (0..4095)
__global__ __launch_bounds__(256) void qkv_rope_k(const u16* __restrict__ xb, const u16* __restrict__ Wab,
                                                  const float* __restrict__ bias,
                                                  const float2* __restrict__ tab,
                                                  u16* __restrict__ qb, u16* __restrict__ kb,
                                                  u16* __restrict__ vt) {
    __shared__ u16 smem[24576];               // As[3][4096] | Bs[3][4096] = 48KB; Ct[17408] unions
    u16* As = smem;                           // [buf][128][32] linear (content swizzled)
    u16* Bs = smem + 12288;
    int tid = threadIdx.x;
    int n0 = blockIdx.x * 128, m0 = blockIdx.y * 128;
    int w = tid >> 6, lane = tid & 63, lr = lane & 15, quad = lane >> 4;
    int wr = w >> 1, wc = w & 1;
    f32x4 acc[4][4] = {};
    int srow = tid >> 2;                                  // staging row 0..63 (+64 second half)
    int swc8 = (((tid & 3) ^ (srow & 3)) << 3);           // pre-swizzled src col (u16)
    int soff = tid * 8;                                   // linear LDS u16 offset
    int rc8 = ((quad ^ (lr & 3)) << 3);                   // swizzled fragment-read col

#define QKV_STAGE(bufi, kc) do {                                                   \
        int _b = (bufi) * 4096;                                                    \
        gload16(xb  + (size_t)(m0 + srow) * C_EMB + (kc) + swc8,      &As[_b + soff]);        \
        gload16(xb  + (size_t)(m0 + 64 + srow) * C_EMB + (kc) + swc8, &As[_b + 2048 + soff]); \
        gload16(Wab + (size_t)(n0 + srow) * C_EMB + (kc) + swc8,      &Bs[_b + soff]);        \
        gload16(Wab + (size_t)(n0 + 64 + srow) * C_EMB + (kc) + swc8, &Bs[_b + 2048 + soff]); \
    } while (0)

    QKV_STAGE(0, 0);
    QKV_STAGE(1, 32);
    int cur = 0;
    for (int kt = 0; kt < 32; ++kt) {
        if (kt < 30) {
            int nb = cur + 2; if (nb >= 3) nb -= 3;
            QKV_STAGE(nb, (kt + 2) * 32);
            asm volatile("s_waitcnt vmcnt(8)" ::: "memory");   // tile-kt loads done
        } else if (kt == 30) {
            asm volatile("s_waitcnt vmcnt(4)" ::: "memory");
        } else {
            asm volatile("s_waitcnt vmcnt(0)" ::: "memory");
        }
        __builtin_amdgcn_s_barrier();
        asm volatile("" ::: "memory");
        int cb = cur * 4096;
        s16x8 af[4], bf[4];
#pragma unroll
        for (int i = 0; i < 4; ++i)
            af[i] = *(const s16x8*)&As[cb + (wr * 64 + i * 16 + lr) * 32 + rc8];
#pragma unroll
        for (int j = 0; j < 4; ++j)
            bf[j] = *(const s16x8*)&Bs[cb + (wc * 64 + j * 16 + lr) * 32 + rc8];
#pragma unroll
        for (int i = 0; i < 4; ++i)
#pragma unroll
            for (int j = 0; j < 4; ++j) acc[i][j] = MFMA16(af[i], bf[j], acc[i][j]);
        asm volatile("" ::: "memory");
        __builtin_amdgcn_s_barrier();
        cur = cur + 1; if (cur >= 3) cur -= 3;
    }
#undef QKV_STAGE

    int sec = n0 >> 10;                       // 0=q 1=k 2=v (blocks never straddle)
    float bv[4];
#pragma unroll
    for (int j = 0; j < 4; ++j) bv[j] = bias[n0 + wc * 64 + j * 16 + lr];

    int h0 = (n0 & 1023) >> 6;
    int b = m0 >> 11, tbase = m0 & 2047;
    if (sec == 2) {
        // C tile (+bias) -> LDS [d][m] (136-padded) -> coalesced 16B
        // transposed stores to vt[((b*16+h)*64+d)*2048 + t].
        u16* Ct = smem;                        // 128 x 136 u16 = 34816 B
#pragma unroll
        for (int i = 0; i < 4; ++i)
#pragma unroll
            for (int j = 0; j < 4; ++j) {
                f32x4 vv;
#pragma unroll
                for (int r = 0; r < 4; ++r) vv[r] = acc[i][j][r] + bv[j];
                int d = wc * 64 + j * 16 + lr;
                int m4 = wr * 64 + i * 16 + quad * 4;
                *(u16x4*)&Ct[d * 136 + m4] = pack4(vv);
            }
        __syncthreads();
        size_t hb = (size_t)(b * NH);
#pragma unroll
        for (int p = 0; p < 8; ++p) {
            int idx = p * 256 + tid;
            int d = idx >> 4, mc = (idx & 15) << 3;
            s16x8 vdat = *(const s16x8*)&Ct[d * 136 + mc];
            int h = h0 + (d >> 6), dd = d & 63;
            *(s16x8*)(vt + ((hb + h) * HD + dd) * T_SEQ + tbase + mc) = vdat;
        }
    } else {
        // q/k: RoPE in-register, stage [m][n] in LDS, coalesced b128 stores.
        u16* dst = (sec == 0) ? qb : kb;
        // fold 1/sqrt(D) AND log2(e) into q so flash softmax is native base-2:
        float qs = (sec == 0) ? 0.18033688011112043f : 1.0f;
        u16* Ct = smem;                        // 128 x 136 u16
        __syncthreads();                       // all frag reads done before overwrite
#pragma unroll
        for (int i = 0; i < 4; ++i)
#pragma unroll
            for (int r = 0; r < 4; ++r) {
                int mrow = wr * 64 + i * 16 + quad * 4 + r;
                int t = (m0 + mrow) & 2047;
#pragma unroll
                for (int j = 0; j < 2; ++j) {
                    int d1 = j * 16 + lr;                 // 0..31; partner +32 in tile j+2
                    float2 cs = tab[t * 32 + d1];
                    float v1 = acc[i][j][r] + bv[j];
                    float v2 = acc[i][j + 2][r] + bv[j + 2];
                    int n1 = wc * 64 + j * 16 + lr;
                    Ct[mrow * 136 + n1]      = f2bf((v1 * cs.x - v2 * cs.y) * qs);
                    Ct[mrow * 136 + n1 + 32] = f2bf((v2 * cs.x + v1 * cs.y) * qs);
                }
            }
        __syncthreads();
#pragma unroll
        for (int p = 0; p < 8; ++p) {
            int idx = p * 256 + tid;              // 128 rows x 16 chunks of 8 u16
            int mrow = idx >> 4, c = idx & 15;
            s16x8 vdat = *(const s16x8*)&Ct[mrow * 136 + c * 8];
            int h = h0 + (c >> 3), dd = (c & 7) << 3;
            *(s16x8*)(dst + ((size_t)(b * NH + h) * T_SEQ + tbase + mrow) * HD + dd) = vdat;
        }
    }
}

// ---------------- k2: flash attention (64-row tiles, V from global L2) -----
// grid (32, 32), 256 threads / 4 waves / 1 strip each. qt = 64-row q-tile;
// wave w owns rows [qt*64+16w, +16). K staged in dbuf LDS (18.4KB total ->
// 8 blocks/CU capacity, VGPR<=64 via launch_bounds(256,8)); V^T fragments
// read DIRECTLY from global vt (b64/lane, L2-resident 256KB/kt chip-wide,
// issued ~300cy before PV). Short blocks retire -> backfill kills CU drain.
// S^T: elem (k'=k0+tc*16+quad*4+r, q=rbase+lr). PV: 16x16x16, P in regs.
__global__ __launch_bounds__(256, 8) void flash_k(const u16* __restrict__ qb, const u16* __restrict__ kb,
                                                  const u16* __restrict__ vt, u16* __restrict__ yab) {
    __shared__ u16 Ks[2][64 * 72];            // 18432 B total
    int tid = threadIdx.x;
    int bx = blockIdx.x, by = blockIdx.y;
    int qt = (by < 16) ? (31 - bx) : bx;      // complementary pairing for balance
    int bh = by;
    int w = tid >> 6, lane = tid & 63, lr = lane & 15, quad = lane >> 4;
    int q0 = qt * 64;
    const u16* qh = qb + (size_t)bh * T_SEQ * HD;
    const u16* kh = kb + (size_t)bh * T_SEQ * HD;
    const u16* vh = vt + (size_t)bh * HD * T_SEQ;

    int rbase = q0 + w * 16;                  // this wave's strip

    s16x8 aq[2];                              // B-frag of Q (n=q-row=lr, k=d)
#pragma unroll
    for (int ks = 0; ks < 2; ++ks)
        aq[ks] = *(const s16x8*)(qh + (size_t)(rbase + lr) * HD + ks * 32 + quad * 8);

    int srow = tid >> 3, sc8 = (tid & 7) << 3;   // K staging: rows srow, srow+32

    float m_i = -1e30f;
    f32x4 l4 = {0.f, 0.f, 0.f, 0.f};          // per-lane l partials
    f32x4 oacc[4] = {};                       // O^T: elem (d=dn*16+quad*4+r, q=lr)

    int ktmax = qt;
    {   // prologue: stage K tile 0 into buffer 0 (2 rows / thread)
        s16x8 ka = *(const s16x8*)(kh + (size_t)srow * HD + sc8);
        s16x8 kb2 = *(const s16x8*)(kh + (size_t)(srow + 32) * HD + sc8);
        *(s16x8*)&Ks[0][srow * 72 + sc8] = ka;
        *(s16x8*)&Ks[0][(srow + 32) * 72 + sc8] = kb2;
    }
    __syncthreads();

    for (int kt = 0; kt <= ktmax; ++kt) {
        int cur = kt & 1;
        int k0 = kt * 64;
        bool pf = kt < ktmax;
        s16x8 kr0, kr1;                       // next K tile prefetch registers
        if (pf) {
            int kn = k0 + 64;
            kr0 = *(const s16x8*)(kh + (size_t)(kn + srow) * HD + sc8);
            kr1 = *(const s16x8*)(kh + (size_t)(kn + srow + 32) * HD + sc8);
        }
        const u16* Kc = Ks[cur];

        // K fragments from LDS; V^T fragments directly from global (L2)
        s16x8 ak[2][4];                       // K frag (m=k-row=lr, k=d)
#pragma unroll
        for (int ks = 0; ks < 2; ++ks)
#pragma unroll
            for (int tc = 0; tc < 4; ++tc)
                ak[ks][tc] = *(const s16x8*)&Kc[(tc * 16 + lr) * 72 + ks * 32 + quad * 8];
        s16x4 av[4][4];                       // V^T frag (m=d=dn*16+lr, k=tc*16+quad*4+j)
#pragma unroll
        for (int dn = 0; dn < 4; ++dn) {
            const u16* vrow = vh + (size_t)(dn * 16 + lr) * T_SEQ + k0 + quad * 4;
#pragma unroll
            for (int tc = 0; tc < 4; ++tc)
                av[dn][tc] = *(const s16x4*)(vrow + tc * 16);
        }
        f32x4 sacc[4] = {};
#pragma unroll
        for (int ks = 0; ks < 2; ++ks)
#pragma unroll
            for (int tc = 0; tc < 4; ++tc) sacc[tc] = MFMA16(ak[ks][tc], aq[ks], sacc[tc]);
        if (kt == ktmax) {                    // diagonal tile: causal mask
#pragma unroll
            for (int tc = 0; tc < 4; ++tc)
#pragma unroll
                for (int r = 0; r < 4; ++r)
                    if (k0 + tc * 16 + quad * 4 + r > rbase + lr) sacc[tc][r] = -1e30f;
        }
        // per-lane local max; __all == row-max guard
        f32x4 mv = sacc[0];
#pragma unroll
        for (int tc = 1; tc < 4; ++tc)
#pragma unroll
            for (int r = 0; r < 4; ++r) mv[r] = fmaxf(mv[r], sacc[tc][r]);
        float loc = fmaxf(fmaxf(mv[0], mv[1]), fmaxf(mv[2], mv[3]));
        bool need = !__all(loc <= m_i + 8.0f);   // defer-max (T13, THR=8)
        float alpha = 1.0f;
        if (need) {                            // rare: full cross-lane max
            float mx = fmaxf(loc, __shfl_xor(loc, 16, 64));
            mx = fmaxf(mx, __shfl_xor(mx, 32, 64));
            float mn = fmaxf(m_i, mx);
            alpha = __builtin_exp2f(m_i - mn);
            m_i = mn;
#pragma unroll
            for (int r = 0; r < 4; ++r) l4[r] *= alpha;
        }
        float mnow = m_i;
#pragma unroll
        for (int tc = 0; tc < 4; ++tc)
#pragma unroll
            for (int r = 0; r < 4; ++r) {
                float p = __builtin_exp2f(sacc[tc][r] - mnow);
                sacc[tc][r] = p;
                l4[r] += p;                    // per-lane partial; folded at end
            }
        // P in registers: pack4cvt(sacc[tc]) IS the 16x16x16 B-frag
        s16x4 pa[4];
#pragma unroll
        for (int tc = 0; tc < 4; ++tc) pa[tc] = pack4cvt_s(sacc[tc]);
        if (need) {
#pragma unroll
            for (int dn = 0; dn < 4; ++dn)
#pragma unroll
                for (int r = 0; r < 4; ++r) oacc[dn][r] *= alpha;
        }
#pragma unroll
        for (int dn = 0; dn < 4; ++dn)
#pragma unroll
            for (int tc = 0; tc < 4; ++tc)
                oacc[dn] = MFMA16K16(av[dn][tc], pa[tc], oacc[dn]);

        if (pf) {                              // write prefetched K to other buffer
            int nx = cur ^ 1;
            *(s16x8*)&Ks[nx][srow * 72 + sc8] = kr0;
            *(s16x8*)&Ks[nx][(srow + 32) * 72 + sc8] = kr1;
        }
        __syncthreads();                       // single barrier per k-tile
    }
    // fold l partials: 4 per-lane + the 4 lanes of each row (xor 16, 32)
    float rs = (l4[0] + l4[1]) + (l4[2] + l4[3]);
    rs += __shfl_xor(rs, 16, 64);
    rs += __shfl_xor(rs, 32, 64);
    int b = bh >> 4, hh = bh & 15;
    {
        float inv = 1.f / rs;
        int t = rbase + lr;
        size_t base = ((size_t)b * T_SEQ + t) * C_EMB + hh * HD;
#pragma unroll
        for (int dn = 0; dn < 4; ++dn) {
            f32x4 vv;
#pragma unroll
            for (int r = 0; r < 4; ++r) vv[r] = oacc[dn][r] * inv;
            *(u16x4*)(yab + base + dn * 16 + quad * 4) = pack4(vv);
        }
    }
}

// ---------------- k3: output projection (64x64 tiles, pipelined, dbuf) -----
// grid (16, 64): n0 = bx*64, m0 = by*64. 256 thr / 4 waves; wave (wr,wc)
// owns 32x32 (acc[2][2]). 4 blocks/CU x 4 waves = 16 waves/CU.
__global__ __launch_bounds__(256) void proj_k(const u16* __restrict__ ya, const u16* __restrict__ Wpb,
                                              const float* __restrict__ bias, float* __restrict__ out) {
    __shared__ u16 As[2][2048];               // [buf][64][32] linear (content swizzled)
    __shared__ u16 Bs[2][2048];
    int tid = threadIdx.x;
    int n0 = blockIdx.x * 64, m0 = blockIdx.y * 64;
    int w = tid >> 6, lane = tid & 63, lr = lane & 15, quad = lane >> 4;
    int wr = w >> 1, wc = w & 1;
    f32x4 acc[2][2] = {};
    int srow = tid >> 2;                                  // staging row 0..63
    int swc8 = (((tid & 3) ^ (srow & 3)) << 3);           // pre-swizzled src col (u16)
    int soff = tid * 8;                                   // linear LDS u16 offset
    int rc8 = ((quad ^ (lr & 3)) << 3);                   // swizzled fragment-read col

#define PRJ_STAGE(bufi, kc) do {                                                   \
        gload16(ya  + (size_t)(m0 + srow) * C_EMB + (kc) + swc8, &As[bufi][soff]); \
        gload16(Wpb + (size_t)(n0 + srow) * C_EMB + (kc) + swc8, &Bs[bufi][soff]); \
    } while (0)

    PRJ_STAGE(0, 0);
#pragma unroll 2
    for (int kt = 0; kt < 32; ++kt) {
        int cur = kt & 1;
        if (kt < 31) {
            PRJ_STAGE(cur ^ 1, (kt + 1) * 32);
            asm volatile("s_waitcnt vmcnt(2)" ::: "memory");
        } else {
            asm volatile("s_waitcnt vmcnt(0)" ::: "memory");
        }
        __builtin_amdgcn_s_barrier();
        asm volatile("" ::: "memory");
        s16x8 af[2], bf[2];
#pragma unroll
        for (int i = 0; i < 2; ++i)
            af[i] = *(const s16x8*)&As[cur][(wr * 32 + i * 16 + lr) * 32 + rc8];
#pragma unroll
        for (int j = 0; j < 2; ++j)
            bf[j] = *(const s16x8*)&Bs[cur][(wc * 32 + j * 16 + lr) * 32 + rc8];
#pragma unroll
        for (int i = 0; i < 2; ++i)
#pragma unroll
            for (int j = 0; j < 2; ++j) acc[i][j] = MFMA16(af[i], bf[j], acc[i][j]);
        asm volatile("" ::: "memory");
        __builtin_amdgcn_s_barrier();
    }
#undef PRJ_STAGE

    float bv[2];
#pragma unroll
    for (int j = 0; j < 2; ++j) bv[j] = bias[n0 + wc * 32 + j * 16 + lr];
#pragma unroll
    for (int i = 0; i < 2; ++i)
#pragma unroll
        for (int r = 0; r < 4; ++r) {
            int m = m0 + wr * 32 + i * 16 + quad * 4 + r;
#pragma unroll
            for (int j = 0; j < 2; ++j)
                out[(size_t)m * C_EMB + n0 + wc * 32 + j * 16 + lr] = acc[i][j][r] + bv[j];
        }
}

extern "C" void kernel_launch(void* const* d_in, const int* in_sizes, int n_in,
                              void* d_out, int out_size, void* d_ws, size_t ws_size,
                              hipStream_t stream) {
    // Inputs resolved BY ELEMENT COUNT (unique): x 4194304, W_attn 3145728,
    // b_attn 3072, W_proj 1048576, b_proj 1024. All fp32.
    const float *x = nullptr, *Wa = nullptr, *ba = nullptr, *Wp = nullptr, *bp = nullptr;
    for (int i = 0; i < n_in; ++i) {
        switch (in_sizes[i]) {
            case 4194304: x  = (const float*)d_in[i]; break;
            case 3145728: Wa = (const float*)d_in[i]; break;
            case 3072:    ba = (const float*)d_in[i]; break;
            case 1048576: Wp = (const float*)d_in[i]; break;
            case 1024:    bp = (const float*)d_in[i]; break;
            default: break;
        }
    }
    float* out = (float*)d_out;

    char* ws = (char*)d_ws;
    u16* qb     = (u16*)(ws);                    //  0.. 8 MiB  bf16 [B,H,T,D] (q*0.125*log2e)
    u16* kb     = (u16*)(ws + 8388608);          //  8..16 MiB  bf16 [B,H,T,D]
    u16* vt     = (u16*)(ws + 16777216);         // 16..24 MiB  bf16 [B,H,D,T]
    u16* yab    = (u16*)(ws + 25165824);         // 24..32 MiB  bf16 [B,T,C]
    float2* tab = (float2*)(ws + 33554432);      // 32..32.5 MiB
    u16* xb     = (u16*)(ws + 35651584);         // 34..42 MiB  bf16 [4096,1024]
    u16* Wab    = (u16*)(ws + 44040192);         // 42..48 MiB  bf16 [3072,1024]
    u16* Wpb    = (u16*)(ws + 50331648);         // 48..50 MiB  bf16 [1024,1024]

    prep_k<<<4352, 256, 0, stream>>>(x, Wa, Wp, xb, Wab, Wpb, tab);
    qkv_rope_k<<<dim3(24, 32), 256, 0, stream>>>(xb, Wab, ba, tab, qb, kb, vt);
    flash_k<<<dim3(32, 32), 256, 0, stream>>>(qb, kb, vt, yab);
    proj_k<<<dim3(16, 64), 256, 0, stream>>>(yab, Wpb, bp, out);
}

// Round 13
// 276.824 us; speedup vs baseline: 1.3353x; 1.3353x over previous
//
#include <hip/hip_runtime.h>

// B=2, T=2048, C=1024, H=16, D=64. Inputs fp32, OUTPUT fp32.
// Round 25 (post-mortem R24: launch_bounds(256,8) forced VGPR 32 -> massive
// scratch spill (WRITE_SIZE 301MB, MfmaUtil 4%, 240us). The backfill idea was
// invalidated by the spill, not refuted):
//  - flash_k: identical to R24 but __launch_bounds__(256, 4) — 128-VGPR
//    budget, no spill (kernel naturally ~52-60). LDS 18.4KB still allows
//    8 blocks/CU if allocator lands <=64 VGPR (backfill test); degrades to
//    R21's known-good 4 blocks/CU otherwise. V^T frags read directly from
//    global vt (L2-resident); K staged in dbuf LDS.
//  - prep_k / qkv_rope_k / proj_k unchanged.
// MFMA 16x16x32_bf16 layouts (HW-verified): A: m=lane&15,k=quad*8+j;
// B: k=quad*8+j,n=lane&15; C/D: col=lane&15,row=quad*4+reg.
// MFMA 16x16x16_bf16 (HW-verified R17): A: m=lane&15,k=quad*4+j;
// B: k=quad*4+j,n=lane&15; C/D: col=lane&15,row=quad*4+reg.

typedef unsigned short u16;
typedef u16 u16x4 __attribute__((ext_vector_type(4)));
typedef u16 u16x8 __attribute__((ext_vector_type(8)));
typedef short s16x4 __attribute__((ext_vector_type(4)));
typedef short s16x8 __attribute__((ext_vector_type(8)));
typedef float f32x4 __attribute__((ext_vector_type(4)));

#define T_SEQ 2048
#define C_EMB 1024
#define NH 16
#define HD 64

#define MFMA16(a, b, c) __builtin_amdgcn_mfma_f32_16x16x32_bf16(a, b, c, 0, 0, 0)

__device__ __forceinline__ f32x4 MFMA16K16(s16x4 a, s16x4 b, f32x4 c) {
#if __has_builtin(__builtin_amdgcn_mfma_f32_16x16x16bf16_1k)
    return __builtin_amdgcn_mfma_f32_16x16x16bf16_1k(a, b, c, 0, 0, 0);
#else
    asm("v_mfma_f32_16x16x16_bf16 %0, %1, %2, %0" : "+v"(c) : "v"(a), "v"(b));
    return c;
#endif
}

__device__ __forceinline__ u16 f2bf(float f) {
    union { float f; unsigned int i; } x; x.f = f;
    unsigned int r = x.i + 0x7fffu + ((x.i >> 16) & 1u);
    return (u16)(r >> 16);
}
__device__ __forceinline__ u16x4 pack4(f32x4 v) {
    u16x4 o;
#pragma unroll
    for (int j = 0; j < 4; ++j) o[j] = f2bf(v[j]);
    return o;
}
// hot-loop pack: HW packed convert (RNE), 2 instr per 4 values -> s16x4 frag
__device__ __forceinline__ s16x4 pack4cvt_s(f32x4 v) {
    union { s16x4 h; unsigned int w[2]; } u;
    asm("v_cvt_pk_bf16_f32 %0, %1, %2" : "=v"(u.w[0]) : "v"(v[0]), "v"(v[1]));
    asm("v_cvt_pk_bf16_f32 %0, %1, %2" : "=v"(u.w[1]) : "v"(v[2]), "v"(v[3]));
    return u.h;
}
// async global->LDS, 16B per lane (dest must be wave-uniform base + lane*16)
__device__ __forceinline__ void gload16(const void* g, void* l) {
    __builtin_amdgcn_global_load_lds(
        (const __attribute__((address_space(1))) unsigned int*)g,
        (__attribute__((address_space(3))) unsigned int*)l, 16, 0, 0);
}

// ---------------- k0: merged prep (3x fp32->bf16 conv + rope tables) -------
// grid 4352: [0,2048) conv x; [2048,3584) conv Wa; [3584,4096) conv Wp;
// [4096,4352) rope tables. All sections exact-sized (no bounds checks).
__global__ __launch_bounds__(256) void prep_k(const float* __restrict__ x, const float* __restrict__ Wa,
                                              const float* __restrict__ Wp,
                                              u16* __restrict__ xb, u16* __restrict__ Wab,
                                              u16* __restrict__ Wpb, float2* __restrict__ tab) {
    int bid = blockIdx.x, tid = threadIdx.x;
    if (bid < 4096) {
        const float* src;
        u16* dst;
        int i;
        if (bid < 2048)      { src = x;  dst = xb;  i = bid * 256 + tid; }
        else if (bid < 3584) { src = Wa; dst = Wab; i = (bid - 2048) * 256 + tid; }
        else                 { src = Wp; dst = Wpb; i = (bid - 3584) * 256 + tid; }
        f32x4 a = ((const f32x4*)src)[i * 2];
        f32x4 b = ((const f32x4*)src)[i * 2 + 1];
        u16x8 o;
#pragma unroll
        for (int j = 0; j < 4; ++j) o[j] = f2bf(a[j]);
#pragma unroll
        for (int j = 0; j < 4; ++j) o[4 + j] = f2bf(b[j]);
        ((u16x8*)dst)[i] = o;
    } else {
        int idx = (bid - 4096) * 256 + tid;   // 65536 = T*32
        int t = idx >> 5, j = idx & 31;
        float inv = __builtin_exp2f(-0.41524101186092f * (float)j);  // 10000^(-j/32)
        float s_, c_;
        sincosf((float)t * inv, &s_, &c_);
        tab[idx] = make_float2(c_, s_);
    }
}

// ---------------- k1: QKV GEMM + RoPE (gload_lds, BK=32, 3-deep pipeline) --
// grid (24, 32): n0 = bx*128 (0..3071), m0 = by*128 (0..4095)
__global__ __launch_bounds__(256) void qkv_rope_k(const u16* __restrict__ xb, const u16* __restrict__ Wab,
                                                  const float* __restrict__ bias,
                                                  const float2* __restrict__ tab,
                                                  u16* __restrict__ qb, u16* __restrict__ kb,
                                                  u16* __restrict__ vt) {
    __shared__ u16 smem[24576];               // As[3][4096] | Bs[3][4096] = 48KB; Ct[17408] unions
    u16* As = smem;                           // [buf][128][32] linear (content swizzled)
    u16* Bs = smem + 12288;
    int tid = threadIdx.x;
    int n0 = blockIdx.x * 128, m0 = blockIdx.y * 128;
    int w = tid >> 6, lane = tid & 63, lr = lane & 15, quad = lane >> 4;
    int wr = w >> 1, wc = w & 1;
    f32x4 acc[4][4] = {};
    int srow = tid >> 2;                                  // staging row 0..63 (+64 second half)
    int swc8 = (((tid & 3) ^ (srow & 3)) << 3);           // pre-swizzled src col (u16)
    int soff = tid * 8;                                   // linear LDS u16 offset
    int rc8 = ((quad ^ (lr & 3)) << 3);                   // swizzled fragment-read col

#define QKV_STAGE(bufi, kc) do {                                                   \
        int _b = (bufi) * 4096;                                                    \
        gload16(xb  + (size_t)(m0 + srow) * C_EMB + (kc) + swc8,      &As[_b + soff]);        \
        gload16(xb  + (size_t)(m0 + 64 + srow) * C_EMB + (kc) + swc8, &As[_b + 2048 + soff]); \
        gload16(Wab + (size_t)(n0 + srow) * C_EMB + (kc) + swc8,      &Bs[_b + soff]);        \
        gload16(Wab + (size_t)(n0 + 64 + srow) * C_EMB + (kc) + swc8, &Bs[_b + 2048 + soff]); \
    } while (0)

    QKV_STAGE(0, 0);
    QKV_STAGE(1, 32);
    int cur = 0;
    for (int kt = 0; kt < 32; ++kt) {
        if (kt < 30) {
            int nb = cur + 2; if (nb >= 3) nb -= 3;
            QKV_STAGE(nb, (kt + 2) * 32);
            asm volatile("s_waitcnt vmcnt(8)" ::: "memory");   // tile-kt loads done
        } else if (kt == 30) {
            asm volatile("s_waitcnt vmcnt(4)" ::: "memory");
        } else {
            asm volatile("s_waitcnt vmcnt(0)" ::: "memory");
        }
        __builtin_amdgcn_s_barrier();
        asm volatile("" ::: "memory");
        int cb = cur * 4096;
        s16x8 af[4], bf[4];
#pragma unroll
        for (int i = 0; i < 4; ++i)
            af[i] = *(const s16x8*)&As[cb + (wr * 64 + i * 16 + lr) * 32 + rc8];
#pragma unroll
        for (int j = 0; j < 4; ++j)
            bf[j] = *(const s16x8*)&Bs[cb + (wc * 64 + j * 16 + lr) * 32 + rc8];
#pragma unroll
        for (int i = 0; i < 4; ++i)
#pragma unroll
            for (int j = 0; j < 4; ++j) acc[i][j] = MFMA16(af[i], bf[j], acc[i][j]);
        asm volatile("" ::: "memory");
        __builtin_amdgcn_s_barrier();
        cur = cur + 1; if (cur >= 3) cur -= 3;
    }
#undef QKV_STAGE

    int sec = n0 >> 10;                       // 0=q 1=k 2=v (blocks never straddle)
    float bv[4];
#pragma unroll
    for (int j = 0; j < 4; ++j) bv[j] = bias[n0 + wc * 64 + j * 16 + lr];

    int h0 = (n0 & 1023) >> 6;
    int b = m0 >> 11, tbase = m0 & 2047;
    if (sec == 2) {
        // C tile (+bias) -> LDS [d][m] (136-padded) -> coalesced 16B
        // transposed stores to vt[((b*16+h)*64+d)*2048 + t].
        u16* Ct = smem;                        // 128 x 136 u16 = 34816 B
#pragma unroll
        for (int i = 0; i < 4; ++i)
#pragma unroll
            for (int j = 0; j < 4; ++j) {
                f32x4 vv;
#pragma unroll
                for (int r = 0; r < 4; ++r) vv[r] = acc[i][j][r] + bv[j];
                int d = wc * 64 + j * 16 + lr;
                int m4 = wr * 64 + i * 16 + quad * 4;
                *(u16x4*)&Ct[d * 136 + m4] = pack4(vv);
            }
        __syncthreads();
        size_t hb = (size_t)(b * NH);
#pragma unroll
        for (int p = 0; p < 8; ++p) {
            int idx = p * 256 + tid;
            int d = idx >> 4, mc = (idx & 15) << 3;
            s16x8 vdat = *(const s16x8*)&Ct[d * 136 + mc];
            int h = h0 + (d >> 6), dd = d & 63;
            *(s16x8*)(vt + ((hb + h) * HD + dd) * T_SEQ + tbase + mc) = vdat;
        }
    } else {
        // q/k: RoPE in-register, stage [m][n] in LDS, coalesced b128 stores.
        u16* dst = (sec == 0) ? qb : kb;
        // fold 1/sqrt(D) AND log2(e) into q so flash softmax is native base-2:
        float qs = (sec == 0) ? 0.18033688011112043f : 1.0f;
        u16* Ct = smem;                        // 128 x 136 u16
        __syncthreads();                       // all frag reads done before overwrite
#pragma unroll
        for (int i = 0; i < 4; ++i)
#pragma unroll
            for (int r = 0; r < 4; ++r) {
                int mrow = wr * 64 + i * 16 + quad * 4 + r;
                int t = (m0 + mrow) & 2047;
#pragma unroll
                for (int j = 0; j < 2; ++j) {
                    int d1 = j * 16 + lr;                 // 0..31; partner +32 in tile j+2
                    float2 cs = tab[t * 32 + d1];
                    float v1 = acc[i][j][r] + bv[j];
                    float v2 = acc[i][j + 2][r] + bv[j + 2];
                    int n1 = wc * 64 + j * 16 + lr;
                    Ct[mrow * 136 + n1]      = f2bf((v1 * cs.x - v2 * cs.y) * qs);
                    Ct[mrow * 136 + n1 + 32] = f2bf((v2 * cs.x + v1 * cs.y) * qs);
                }
            }
        __syncthreads();
#pragma unroll
        for (int p = 0; p < 8; ++p) {
            int idx = p * 256 + tid;              // 128 rows x 16 chunks of 8 u16
            int mrow = idx >> 4, c = idx & 15;
            s16x8 vdat = *(const s16x8*)&Ct[mrow * 136 + c * 8];
            int h = h0 + (c >> 3), dd = (c & 7) << 3;
            *(s16x8*)(dst + ((size_t)(b * NH + h) * T_SEQ + tbase + mrow) * HD + dd) = vdat;
        }
    }
}

// ---------------- k2: flash attention (64-row tiles, V from global L2) -----
// grid (32, 32), 256 threads / 4 waves / 1 strip each. qt = 64-row q-tile;
// wave w owns rows [qt*64+16w, +16). K staged in dbuf LDS (18.4KB total);
// V^T fragments read DIRECTLY from global vt (b64/lane, L2-resident,
// issued ~300cy before PV). launch_bounds(256,4): 128-VGPR budget, no
// spill; if allocator lands <=64 VGPR, HW can co-schedule 8 blocks/CU
// (LDS allows 8) -> short blocks retire and fresh blocks backfill.
// S^T: elem (k'=k0+tc*16+quad*4+r, q=rbase+lr). PV: 16x16x16, P in regs.
__global__ __launch_bounds__(256, 4) void flash_k(const u16* __restrict__ qb, const u16* __restrict__ kb,
                                                  const u16* __restrict__ vt, u16* __restrict__ yab) {
    __shared__ u16 Ks[2][64 * 72];            // 18432 B total
    int tid = threadIdx.x;
    int bx = blockIdx.x, by = blockIdx.y;
    int qt = (by < 16) ? (31 - bx) : bx;      // complementary pairing for balance
    int bh = by;
    int w = tid >> 6, lane = tid & 63, lr = lane & 15, quad = lane >> 4;
    int q0 = qt * 64;
    const u16* qh = qb + (size_t)bh * T_SEQ * HD;
    const u16* kh = kb + (size_t)bh * T_SEQ * HD;
    const u16* vh = vt + (size_t)bh * HD * T_SEQ;

    int rbase = q0 + w * 16;                  // this wave's strip

    s16x8 aq[2];                              // B-frag of Q (n=q-row=lr, k=d)
#pragma unroll
    for (int ks = 0; ks < 2; ++ks)
        aq[ks] = *(const s16x8*)(qh + (size_t)(rbase + lr) * HD + ks * 32 + quad * 8);

    int srow = tid >> 3, sc8 = (tid & 7) << 3;   // K staging: rows srow, srow+32

    float m_i = -1e30f;
    f32x4 l4 = {0.f, 0.f, 0.f, 0.f};          // per-lane l partials
    f32x4 oacc[4] = {};                       // O^T: elem (d=dn*16+quad*4+r, q=lr)

    int ktmax = qt;
    {   // prologue: stage K tile 0 into buffer 0 (2 rows / thread)
        s16x8 ka = *(const s16x8*)(kh + (size_t)srow * HD + sc8);
        s16x8 kb2 = *(const s16x8*)(kh + (size_t)(srow + 32) * HD + sc8);
        *(s16x8*)&Ks[0][srow * 72 + sc8] = ka;
        *(s16x8*)&Ks[0][(srow + 32) * 72 + sc8] = kb2;
    }
    __syncthreads();

    for (int kt = 0; kt <= ktmax; ++kt) {
        int cur = kt & 1;
        int k0 = kt * 64;
        bool pf = kt < ktmax;
        s16x8 kr0, kr1;                       // next K tile prefetch registers
        if (pf) {
            int kn = k0 + 64;
            kr0 = *(const s16x8*)(kh + (size_t)(kn + srow) * HD + sc8);
            kr1 = *(const s16x8*)(kh + (size_t)(kn + srow + 32) * HD + sc8);
        }
        const u16* Kc = Ks[cur];

        // K fragments from LDS; V^T fragments directly from global (L2)
        s16x8 ak[2][4];                       // K frag (m=k-row=lr, k=d)
#pragma unroll
        for (int ks = 0; ks < 2; ++ks)
#pragma unroll
            for (int tc = 0; tc < 4; ++tc)
                ak[ks][tc] = *(const s16x8*)&Kc[(tc * 16 + lr) * 72 + ks * 32 + quad * 8];
        s16x4 av[4][4];                       // V^T frag (m=d=dn*16+lr, k=tc*16+quad*4+j)
#pragma unroll
        for (int dn = 0; dn < 4; ++dn) {
            const u16* vrow = vh + (size_t)(dn * 16 + lr) * T_SEQ + k0 + quad * 4;
#pragma unroll
            for (int tc = 0; tc < 4; ++tc)
                av[dn][tc] = *(const s16x4*)(vrow + tc * 16);
        }
        f32x4 sacc[4] = {};
#pragma unroll
        for (int ks = 0; ks < 2; ++ks)
#pragma unroll
            for (int tc = 0; tc < 4; ++tc) sacc[tc] = MFMA16(ak[ks][tc], aq[ks], sacc[tc]);
        if (kt == ktmax) {                    // diagonal tile: causal mask
#pragma unroll
            for (int tc = 0; tc < 4; ++tc)
#pragma unroll
                for (int r = 0; r < 4; ++r)
                    if (k0 + tc * 16 + quad * 4 + r > rbase + lr) sacc[tc][r] = -1e30f;
        }
        // per-lane local max; __all == row-max guard
        f32x4 mv = sacc[0];
#pragma unroll
        for (int tc = 1; tc < 4; ++tc)
#pragma unroll
            for (int r = 0; r < 4; ++r) mv[r] = fmaxf(mv[r], sacc[tc][r]);
        float loc = fmaxf(fmaxf(mv[0], mv[1]), fmaxf(mv[2], mv[3]));
        bool need = !__all(loc <= m_i + 8.0f);   // defer-max (T13, THR=8)
        float alpha = 1.0f;
        if (need) {                            // rare: full cross-lane max
            float mx = fmaxf(loc, __shfl_xor(loc, 16, 64));
            mx = fmaxf(mx, __shfl_xor(mx, 32, 64));
            float mn = fmaxf(m_i, mx);
            alpha = __builtin_exp2f(m_i - mn);
            m_i = mn;
#pragma unroll
            for (int r = 0; r < 4; ++r) l4[r] *= alpha;
        }
        float mnow = m_i;
#pragma unroll
        for (int tc = 0; tc < 4; ++tc)
#pragma unroll
            for (int r = 0; r < 4; ++r) {
                float p = __builtin_exp2f(sacc[tc][r] - mnow);
                sacc[tc][r] = p;
                l4[r] += p;                    // per-lane partial; folded at end
            }
        // P in registers: pack4cvt(sacc[tc]) IS the 16x16x16 B-frag
        s16x4 pa[4];
#pragma unroll
        for (int tc = 0; tc < 4; ++tc) pa[tc] = pack4cvt_s(sacc[tc]);
        if (need) {
#pragma unroll
            for (int dn = 0; dn < 4; ++dn)
#pragma unroll
                for (int r = 0; r < 4; ++r) oacc[dn][r] *= alpha;
        }
#pragma unroll
        for (int dn = 0; dn < 4; ++dn)
#pragma unroll
            for (int tc = 0; tc < 4; ++tc)
                oacc[dn] = MFMA16K16(av[dn][tc], pa[tc], oacc[dn]);

        if (pf) {                              // write prefetched K to other buffer
            int nx = cur ^ 1;
            *(s16x8*)&Ks[nx][srow * 72 + sc8] = kr0;
            *(s16x8*)&Ks[nx][(srow + 32) * 72 + sc8] = kr1;
        }
        __syncthreads();                       // single barrier per k-tile
    }
    // fold l partials: 4 per-lane + the 4 lanes of each row (xor 16, 32)
    float rs = (l4[0] + l4[1]) + (l4[2] + l4[3]);
    rs += __shfl_xor(rs, 16, 64);
    rs += __shfl_xor(rs, 32, 64);
    int b = bh >> 4, hh = bh & 15;
    {
        float inv = 1.f / rs;
        int t = rbase + lr;
        size_t base = ((size_t)b * T_SEQ + t) * C_EMB + hh * HD;
#pragma unroll
        for (int dn = 0; dn < 4; ++dn) {
            f32x4 vv;
#pragma unroll
            for (int r = 0; r < 4; ++r) vv[r] = oacc[dn][r] * inv;
            *(u16x4*)(yab + base + dn * 16 + quad * 4) = pack4(vv);
        }
    }
}

// ---------------- k3: output projection (64x64 tiles, pipelined, dbuf) -----
// grid (16, 64): n0 = bx*64, m0 = by*64. 256 thr / 4 waves; wave (wr,wc)
// owns 32x32 (acc[2][2]). 4 blocks/CU x 4 waves = 16 waves/CU.
__global__ __launch_bounds__(256) void proj_k(const u16* __restrict__ ya, const u16* __restrict__ Wpb,
                                              const float* __restrict__ bias, float* __restrict__ out) {
    __shared__ u16 As[2][2048];               // [buf][64][32] linear (content swizzled)
    __shared__ u16 Bs[2][2048];
    int tid = threadIdx.x;
    int n0 = blockIdx.x * 64, m0 = blockIdx.y * 64;
    int w = tid >> 6, lane = tid & 63, lr = lane & 15, quad = lane >> 4;
    int wr = w >> 1, wc = w & 1;
    f32x4 acc[2][2] = {};
    int srow = tid >> 2;                                  // staging row 0..63
    int swc8 = (((tid & 3) ^ (srow & 3)) << 3);           // pre-swizzled src col (u16)
    int soff = tid * 8;                                   // linear LDS u16 offset
    int rc8 = ((quad ^ (lr & 3)) << 3);                   // swizzled fragment-read col

#define PRJ_STAGE(bufi, kc) do {                                                   \
        gload16(ya  + (size_t)(m0 + srow) * C_EMB + (kc) + swc8, &As[bufi][soff]); \
        gload16(Wpb + (size_t)(n0 + srow) * C_EMB + (kc) + swc8, &Bs[bufi][soff]); \
    } while (0)

    PRJ_STAGE(0, 0);
#pragma unroll 2
    for (int kt = 0; kt < 32; ++kt) {
        int cur = kt & 1;
        if (kt < 31) {
            PRJ_STAGE(cur ^ 1, (kt + 1) * 32);
            asm volatile("s_waitcnt vmcnt(2)" ::: "memory");
        } else {
            asm volatile("s_waitcnt vmcnt(0)" ::: "memory");
        }
        __builtin_amdgcn_s_barrier();
        asm volatile("" ::: "memory");
        s16x8 af[2], bf[2];
#pragma unroll
        for (int i = 0; i < 2; ++i)
            af[i] = *(const s16x8*)&As[cur][(wr * 32 + i * 16 + lr) * 32 + rc8];
#pragma unroll
        for (int j = 0; j < 2; ++j)
            bf[j] = *(const s16x8*)&Bs[cur][(wc * 32 + j * 16 + lr) * 32 + rc8];
#pragma unroll
        for (int i = 0; i < 2; ++i)
#pragma unroll
            for (int j = 0; j < 2; ++j) acc[i][j] = MFMA16(af[i], bf[j], acc[i][j]);
        asm volatile("" ::: "memory");
        __builtin_amdgcn_s_barrier();
    }
#undef PRJ_STAGE

    float bv[2];
#pragma unroll
    for (int j = 0; j < 2; ++j) bv[j] = bias[n0 + wc * 32 + j * 16 + lr];
#pragma unroll
    for (int i = 0; i < 2; ++i)
#pragma unroll
        for (int r = 0; r < 4; ++r) {
            int m = m0 + wr * 32 + i * 16 + quad * 4 + r;
#pragma unroll
            for (int j = 0; j < 2; ++j)
                out[(size_t)m * C_EMB + n0 + wc * 32 + j * 16 + lr] = acc[i][j][r] + bv[j];
        }
}

extern "C" void kernel_launch(void* const* d_in, const int* in_sizes, int n_in,
                              void* d_out, int out_size, void* d_ws, size_t ws_size,
                              hipStream_t stream) {
    // Inputs resolved BY ELEMENT COUNT (unique): x 4194304, W_attn 3145728,
    // b_attn 3072, W_proj 1048576, b_proj 1024. All fp32.
    const float *x = nullptr, *Wa = nullptr, *ba = nullptr, *Wp = nullptr, *bp = nullptr;
    for (int i = 0; i < n_in; ++i) {
        switch (in_sizes[i]) {
            case 4194304: x  = (const float*)d_in[i]; break;
            case 3145728: Wa = (const float*)d_in[i]; break;
            case 3072:    ba = (const float*)d_in[i]; break;
            case 1048576: Wp = (const float*)d_in[i]; break;
            case 1024:    bp = (const float*)d_in[i]; break;
            default: break;
        }
    }
    float* out = (float*)d_out;

    char* ws = (char*)d_ws;
    u16* qb     = (u16*)(ws);                    //  0.. 8 MiB  bf16 [B,H,T,D] (q*0.125*log2e)
    u16* kb     = (u16*)(ws + 8388608);          //  8..16 MiB  bf16 [B,H,T,D]
    u16* vt     = (u16*)(ws + 16777216);         // 16..24 MiB  bf16 [B,H,D,T]
    u16* yab    = (u16*)(ws + 25165824);         // 24..32 MiB  bf16 [B,T,C]
    float2* tab = (float2*)(ws + 33554432);      // 32..32.5 MiB
    u16* xb     = (u16*)(ws + 35651584);         // 34..42 MiB  bf16 [4096,1024]
    u16* Wab    = (u16*)(ws + 44040192);         // 42..48 MiB  bf16 [3072,1024]
    u16* Wpb    = (u16*)(ws + 50331648);         // 48..50 MiB  bf16 [1024,1024]

    prep_k<<<4352, 256, 0, stream>>>(x, Wa, Wp, xb, Wab, Wpb, tab);
    qkv_rope_k<<<dim3(24, 32), 256, 0, stream>>>(xb, Wab, ba, tab, qb, kb, vt);
    flash_k<<<dim3(32, 32), 256, 0, stream>>>(qb, kb, vt, yab);
    proj_k<<<dim3(16, 64), 256, 0, stream>>>(yab, Wpb, bp, out);
}

// Round 14
// 192.171 us; speedup vs baseline: 1.9235x; 1.4405x over previous
//
#include <hip/hip_runtime.h>

// B=2, T=2048, C=1024, H=16, D=64. Inputs fp32, OUTPUT fp32.
// Round 26 (post-mortem R25: V-from-global refuted — av loads are 16-segment
// gathers (lanes stride 4KB), ~256 L2 transactions/tile/wave on the VMEM
// issue path; latency/issue-bound, 142us. Backfill line abandoned):
//  - flash_k: REVERT to R21 exactly (best measured 54.4us: 64-row Q tiles,
//    grid (32,32), 256 thr, V staged in dbuf LDS, 4 blocks/CU, VGPR 52)
//    + T5 s_setprio(1/0) around the QK and PV MFMA clusters (attn-proven
//    +4-7%, m191; this kernel has the multi-block independently-phased
//    wave structure where setprio pays).
//  - prep_k / qkv_rope_k / proj_k unchanged (R21-identical).
// MFMA 16x16x32_bf16 layouts (HW-verified): A: m=lane&15,k=quad*8+j;
// B: k=quad*8+j,n=lane&15; C/D: col=lane&15,row=quad*4+reg.
// MFMA 16x16x16_bf16 (HW-verified R17): A: m=lane&15,k=quad*4+j;
// B: k=quad*4+j,n=lane&15; C/D: col=lane&15,row=quad*4+reg.

typedef unsigned short u16;
typedef u16 u16x4 __attribute__((ext_vector_type(4)));
typedef u16 u16x8 __attribute__((ext_vector_type(8)));
typedef short s16x4 __attribute__((ext_vector_type(4)));
typedef short s16x8 __attribute__((ext_vector_type(8)));
typedef float f32x4 __attribute__((ext_vector_type(4)));

#define T_SEQ 2048
#define C_EMB 1024
#define NH 16
#define HD 64

#define MFMA16(a, b, c) __builtin_amdgcn_mfma_f32_16x16x32_bf16(a, b, c, 0, 0, 0)

__device__ __forceinline__ f32x4 MFMA16K16(s16x4 a, s16x4 b, f32x4 c) {
#if __has_builtin(__builtin_amdgcn_mfma_f32_16x16x16bf16_1k)
    return __builtin_amdgcn_mfma_f32_16x16x16bf16_1k(a, b, c, 0, 0, 0);
#else
    asm("v_mfma_f32_16x16x16_bf16 %0, %1, %2, %0" : "+v"(c) : "v"(a), "v"(b));
    return c;
#endif
}

__device__ __forceinline__ u16 f2bf(float f) {
    union { float f; unsigned int i; } x; x.f = f;
    unsigned int r = x.i + 0x7fffu + ((x.i >> 16) & 1u);
    return (u16)(r >> 16);
}
__device__ __forceinline__ u16x4 pack4(f32x4 v) {
    u16x4 o;
#pragma unroll
    for (int j = 0; j < 4; ++j) o[j] = f2bf(v[j]);
    return o;
}
// hot-loop pack: HW packed convert (RNE), 2 instr per 4 values -> s16x4 frag
__device__ __forceinline__ s16x4 pack4cvt_s(f32x4 v) {
    union { s16x4 h; unsigned int w[2]; } u;
    asm("v_cvt_pk_bf16_f32 %0, %1, %2" : "=v"(u.w[0]) : "v"(v[0]), "v"(v[1]));
    asm("v_cvt_pk_bf16_f32 %0, %1, %2" : "=v"(u.w[1]) : "v"(v[2]), "v"(v[3]));
    return u.h;
}
// async global->LDS, 16B per lane (dest must be wave-uniform base + lane*16)
__device__ __forceinline__ void gload16(const void* g, void* l) {
    __builtin_amdgcn_global_load_lds(
        (const __attribute__((address_space(1))) unsigned int*)g,
        (__attribute__((address_space(3))) unsigned int*)l, 16, 0, 0);
}

// ---------------- k0: merged prep (3x fp32->bf16 conv + rope tables) -------
// grid 4352: [0,2048) conv x; [2048,3584) conv Wa; [3584,4096) conv Wp;
// [4096,4352) rope tables. All sections exact-sized (no bounds checks).
__global__ __launch_bounds__(256) void prep_k(const float* __restrict__ x, const float* __restrict__ Wa,
                                              const float* __restrict__ Wp,
                                              u16* __restrict__ xb, u16* __restrict__ Wab,
                                              u16* __restrict__ Wpb, float2* __restrict__ tab) {
    int bid = blockIdx.x, tid = threadIdx.x;
    if (bid < 4096) {
        const float* src;
        u16* dst;
        int i;
        if (bid < 2048)      { src = x;  dst = xb;  i = bid * 256 + tid; }
        else if (bid < 3584) { src = Wa; dst = Wab; i = (bid - 2048) * 256 + tid; }
        else                 { src = Wp; dst = Wpb; i = (bid - 3584) * 256 + tid; }
        f32x4 a = ((const f32x4*)src)[i * 2];
        f32x4 b = ((const f32x4*)src)[i * 2 + 1];
        u16x8 o;
#pragma unroll
        for (int j = 0; j < 4; ++j) o[j] = f2bf(a[j]);
#pragma unroll
        for (int j = 0; j < 4; ++j) o[4 + j] = f2bf(b[j]);
        ((u16x8*)dst)[i] = o;
    } else {
        int idx = (bid - 4096) * 256 + tid;   // 65536 = T*32
        int t = idx >> 5, j = idx & 31;
        float inv = __builtin_exp2f(-0.41524101186092f * (float)j);  // 10000^(-j/32)
        float s_, c_;
        sincosf((float)t * inv, &s_, &c_);
        tab[idx] = make_float2(c_, s_);
    }
}

// ---------------- k1: QKV GEMM + RoPE (gload_lds, BK=32, 3-deep pipeline) --
// grid (24, 32): n0 = bx*128 (0..3071), m0 = by*128 (0..4095)
__global__ __launch_bounds__(256) void qkv_rope_k(const u16* __restrict__ xb, const u16* __restrict__ Wab,
                                                  const float* __restrict__ bias,
                                                  const float2* __restrict__ tab,
                                                  u16* __restrict__ qb, u16* __restrict__ kb,
                                                  u16* __restrict__ vt) {
    __shared__ u16 smem[24576];               // As[3][4096] | Bs[3][4096] = 48KB; Ct[17408] unions
    u16* As = smem;                           // [buf][128][32] linear (content swizzled)
    u16* Bs = smem + 12288;
    int tid = threadIdx.x;
    int n0 = blockIdx.x * 128, m0 = blockIdx.y * 128;
    int w = tid >> 6, lane = tid & 63, lr = lane & 15, quad = lane >> 4;
    int wr = w >> 1, wc = w & 1;
    f32x4 acc[4][4] = {};
    int srow = tid >> 2;                                  // staging row 0..63 (+64 second half)
    int swc8 = (((tid & 3) ^ (srow & 3)) << 3);           // pre-swizzled src col (u16)
    int soff = tid * 8;                                   // linear LDS u16 offset
    int rc8 = ((quad ^ (lr & 3)) << 3);                   // swizzled fragment-read col

#define QKV_STAGE(bufi, kc) do {                                                   \
        int _b = (bufi) * 4096;                                                    \
        gload16(xb  + (size_t)(m0 + srow) * C_EMB + (kc) + swc8,      &As[_b + soff]);        \
        gload16(xb  + (size_t)(m0 + 64 + srow) * C_EMB + (kc) + swc8, &As[_b + 2048 + soff]); \
        gload16(Wab + (size_t)(n0 + srow) * C_EMB + (kc) + swc8,      &Bs[_b + soff]);        \
        gload16(Wab + (size_t)(n0 + 64 + srow) * C_EMB + (kc) + swc8, &Bs[_b + 2048 + soff]); \
    } while (0)

    QKV_STAGE(0, 0);
    QKV_STAGE(1, 32);
    int cur = 0;
    for (int kt = 0; kt < 32; ++kt) {
        if (kt < 30) {
            int nb = cur + 2; if (nb >= 3) nb -= 3;
            QKV_STAGE(nb, (kt + 2) * 32);
            asm volatile("s_waitcnt vmcnt(8)" ::: "memory");   // tile-kt loads done
        } else if (kt == 30) {
            asm volatile("s_waitcnt vmcnt(4)" ::: "memory");
        } else {
            asm volatile("s_waitcnt vmcnt(0)" ::: "memory");
        }
        __builtin_amdgcn_s_barrier();
        asm volatile("" ::: "memory");
        int cb = cur * 4096;
        s16x8 af[4], bf[4];
#pragma unroll
        for (int i = 0; i < 4; ++i)
            af[i] = *(const s16x8*)&As[cb + (wr * 64 + i * 16 + lr) * 32 + rc8];
#pragma unroll
        for (int j = 0; j < 4; ++j)
            bf[j] = *(const s16x8*)&Bs[cb + (wc * 64 + j * 16 + lr) * 32 + rc8];
#pragma unroll
        for (int i = 0; i < 4; ++i)
#pragma unroll
            for (int j = 0; j < 4; ++j) acc[i][j] = MFMA16(af[i], bf[j], acc[i][j]);
        asm volatile("" ::: "memory");
        __builtin_amdgcn_s_barrier();
        cur = cur + 1; if (cur >= 3) cur -= 3;
    }
#undef QKV_STAGE

    int sec = n0 >> 10;                       // 0=q 1=k 2=v (blocks never straddle)
    float bv[4];
#pragma unroll
    for (int j = 0; j < 4; ++j) bv[j] = bias[n0 + wc * 64 + j * 16 + lr];

    int h0 = (n0 & 1023) >> 6;
    int b = m0 >> 11, tbase = m0 & 2047;
    if (sec == 2) {
        // C tile (+bias) -> LDS [d][m] (136-padded) -> coalesced 16B
        // transposed stores to vt[((b*16+h)*64+d)*2048 + t].
        u16* Ct = smem;                        // 128 x 136 u16 = 34816 B
#pragma unroll
        for (int i = 0; i < 4; ++i)
#pragma unroll
            for (int j = 0; j < 4; ++j) {
                f32x4 vv;
#pragma unroll
                for (int r = 0; r < 4; ++r) vv[r] = acc[i][j][r] + bv[j];
                int d = wc * 64 + j * 16 + lr;
                int m4 = wr * 64 + i * 16 + quad * 4;
                *(u16x4*)&Ct[d * 136 + m4] = pack4(vv);
            }
        __syncthreads();
        size_t hb = (size_t)(b * NH);
#pragma unroll
        for (int p = 0; p < 8; ++p) {
            int idx = p * 256 + tid;
            int d = idx >> 4, mc = (idx & 15) << 3;
            s16x8 vdat = *(const s16x8*)&Ct[d * 136 + mc];
            int h = h0 + (d >> 6), dd = d & 63;
            *(s16x8*)(vt + ((hb + h) * HD + dd) * T_SEQ + tbase + mc) = vdat;
        }
    } else {
        // q/k: RoPE in-register, stage [m][n] in LDS, coalesced b128 stores.
        u16* dst = (sec == 0) ? qb : kb;
        // fold 1/sqrt(D) AND log2(e) into q so flash softmax is native base-2:
        float qs = (sec == 0) ? 0.18033688011112043f : 1.0f;
        u16* Ct = smem;                        // 128 x 136 u16
        __syncthreads();                       // all frag reads done before overwrite
#pragma unroll
        for (int i = 0; i < 4; ++i)
#pragma unroll
            for (int r = 0; r < 4; ++r) {
                int mrow = wr * 64 + i * 16 + quad * 4 + r;
                int t = (m0 + mrow) & 2047;
#pragma unroll
                for (int j = 0; j < 2; ++j) {
                    int d1 = j * 16 + lr;                 // 0..31; partner +32 in tile j+2
                    float2 cs = tab[t * 32 + d1];
                    float v1 = acc[i][j][r] + bv[j];
                    float v2 = acc[i][j + 2][r] + bv[j + 2];
                    int n1 = wc * 64 + j * 16 + lr;
                    Ct[mrow * 136 + n1]      = f2bf((v1 * cs.x - v2 * cs.y) * qs);
                    Ct[mrow * 136 + n1 + 32] = f2bf((v2 * cs.x + v1 * cs.y) * qs);
                }
            }
        __syncthreads();
#pragma unroll
        for (int p = 0; p < 8; ++p) {
            int idx = p * 256 + tid;              // 128 rows x 16 chunks of 8 u16
            int mrow = idx >> 4, c = idx & 15;
            s16x8 vdat = *(const s16x8*)&Ct[mrow * 136 + c * 8];
            int h = h0 + (c >> 3), dd = (c & 7) << 3;
            *(s16x8*)(dst + ((size_t)(b * NH + h) * T_SEQ + tbase + mrow) * HD + dd) = vdat;
        }
    }
}

// ---------------- k2: flash attention (64-row Q tile, 4 blocks/CU) ---------
// grid (32, 32), 256 threads / 4 waves / 1 strip each. qt = q-tile of 64
// rows; wave w owns rows [qt*64+16w, +16). 1024 blocks = 4 blocks/CU
// (LDS 36.9KB). Every strip active in every tile; mask only on kt==qt.
// S^T: elem (k'=k0+tc*16+quad*4+r, q=rbase+lr). PV: 16x16x16, P in regs.
// Double-buffered K/V LDS, one barrier per k-tile. T5 setprio around MFMAs.
__global__ __launch_bounds__(256, 4) void flash_k(const u16* __restrict__ qb, const u16* __restrict__ kb,
                                                  const u16* __restrict__ vt, u16* __restrict__ yab) {
    __shared__ u16 Ks[2][64 * 72];
    __shared__ u16 Vs[2][64 * 72];
    int tid = threadIdx.x;
    int bx = blockIdx.x, by = blockIdx.y;
    int qt = (by < 16) ? (31 - bx) : bx;      // complementary pairing for balance
    int bh = by;
    int w = tid >> 6, lane = tid & 63, lr = lane & 15, quad = lane >> 4;
    int q0 = qt * 64;
    const u16* qh = qb + (size_t)bh * T_SEQ * HD;
    const u16* kh = kb + (size_t)bh * T_SEQ * HD;
    const u16* vh = vt + (size_t)bh * HD * T_SEQ;

    int rbase = q0 + w * 16;                  // this wave's strip

    s16x8 aq[2];                              // B-frag of Q (n=q-row=lr, k=d)
#pragma unroll
    for (int ks = 0; ks < 2; ++ks)
        aq[ks] = *(const s16x8*)(qh + (size_t)(rbase + lr) * HD + ks * 32 + quad * 8);

    int srow = tid >> 3, sc8 = (tid & 7) << 3;   // staging: rows srow, srow+32

    float m_i = -1e30f;
    f32x4 l4 = {0.f, 0.f, 0.f, 0.f};          // per-lane l partials
    f32x4 oacc[4] = {};                       // O^T: elem (d=dn*16+quad*4+r, q=lr)

    int ktmax = qt;
    {   // prologue: stage tile 0 into buffer 0 (2 K-rows + 2 V-rows / thread)
        s16x8 ka = *(const s16x8*)(kh + (size_t)srow * HD + sc8);
        s16x8 kb2 = *(const s16x8*)(kh + (size_t)(srow + 32) * HD + sc8);
        s16x8 va = *(const s16x8*)(vh + (size_t)srow * T_SEQ + sc8);
        s16x8 vb = *(const s16x8*)(vh + (size_t)(srow + 32) * T_SEQ + sc8);
        *(s16x8*)&Ks[0][srow * 72 + sc8] = ka;
        *(s16x8*)&Ks[0][(srow + 32) * 72 + sc8] = kb2;
        *(s16x8*)&Vs[0][srow * 72 + sc8] = va;
        *(s16x8*)&Vs[0][(srow + 32) * 72 + sc8] = vb;
    }
    __syncthreads();

    for (int kt = 0; kt <= ktmax; ++kt) {
        int cur = kt & 1;
        int k0 = kt * 64;
        bool pf = kt < ktmax;
        s16x8 kr0, kr1, vr0, vr1;             // next-tile prefetch registers
        if (pf) {
            int kn = k0 + 64;
            kr0 = *(const s16x8*)(kh + (size_t)(kn + srow) * HD + sc8);
            kr1 = *(const s16x8*)(kh + (size_t)(kn + srow + 32) * HD + sc8);
            vr0 = *(const s16x8*)(vh + (size_t)srow * T_SEQ + kn + sc8);
            vr1 = *(const s16x8*)(vh + (size_t)(srow + 32) * T_SEQ + kn + sc8);
        }
        const u16* Kc = Ks[cur];
        const u16* Vc = Vs[cur];

        // fragments (all strips active every tile in the 64-row form)
        s16x8 ak[2][4];                       // K frag (m=k-row=lr, k=d)
#pragma unroll
        for (int ks = 0; ks < 2; ++ks)
#pragma unroll
            for (int tc = 0; tc < 4; ++tc)
                ak[ks][tc] = *(const s16x8*)&Kc[(tc * 16 + lr) * 72 + ks * 32 + quad * 8];
        s16x4 av[4][4];                       // V^T frag (m=d=dn*16+lr, k=tc*16+quad*4+j)
#pragma unroll
        for (int dn = 0; dn < 4; ++dn) {
            const u16* vrow = &Vc[(dn * 16 + lr) * 72 + quad * 4];
#pragma unroll
            for (int tc = 0; tc < 4; ++tc)
                av[dn][tc] = *(const s16x4*)(vrow + tc * 16);
        }
        f32x4 sacc[4] = {};
        __builtin_amdgcn_s_setprio(1);        // T5: favor MFMA wave
#pragma unroll
        for (int ks = 0; ks < 2; ++ks)
#pragma unroll
            for (int tc = 0; tc < 4; ++tc) sacc[tc] = MFMA16(ak[ks][tc], aq[ks], sacc[tc]);
        __builtin_amdgcn_s_setprio(0);
        if (kt == ktmax) {                    // diagonal tile: causal mask
#pragma unroll
            for (int tc = 0; tc < 4; ++tc)
#pragma unroll
                for (int r = 0; r < 4; ++r)
                    if (k0 + tc * 16 + quad * 4 + r > rbase + lr) sacc[tc][r] = -1e30f;
        }
        // per-lane local max; __all == row-max guard
        f32x4 mv = sacc[0];
#pragma unroll
        for (int tc = 1; tc < 4; ++tc)
#pragma unroll
            for (int r = 0; r < 4; ++r) mv[r] = fmaxf(mv[r], sacc[tc][r]);
        float loc = fmaxf(fmaxf(mv[0], mv[1]), fmaxf(mv[2], mv[3]));
        bool need = !__all(loc <= m_i + 8.0f);   // defer-max (T13, THR=8)
        float alpha = 1.0f;
        if (need) {                            // rare: full cross-lane max
            float mx = fmaxf(loc, __shfl_xor(loc, 16, 64));
            mx = fmaxf(mx, __shfl_xor(mx, 32, 64));
            float mn = fmaxf(m_i, mx);
            alpha = __builtin_exp2f(m_i - mn);
            m_i = mn;
#pragma unroll
            for (int r = 0; r < 4; ++r) l4[r] *= alpha;
        }
        float mnow = m_i;
#pragma unroll
        for (int tc = 0; tc < 4; ++tc)
#pragma unroll
            for (int r = 0; r < 4; ++r) {
                float p = __builtin_exp2f(sacc[tc][r] - mnow);
                sacc[tc][r] = p;
                l4[r] += p;                    // per-lane partial; folded at end
            }
        // P in registers: pack4cvt(sacc[tc]) IS the 16x16x16 B-frag
        s16x4 pa[4];
#pragma unroll
        for (int tc = 0; tc < 4; ++tc) pa[tc] = pack4cvt_s(sacc[tc]);
        if (need) {
#pragma unroll
            for (int dn = 0; dn < 4; ++dn)
#pragma unroll
                for (int r = 0; r < 4; ++r) oacc[dn][r] *= alpha;
        }
        __builtin_amdgcn_s_setprio(1);        // T5: favor MFMA wave
#pragma unroll
        for (int dn = 0; dn < 4; ++dn)
#pragma unroll
            for (int tc = 0; tc < 4; ++tc)
                oacc[dn] = MFMA16K16(av[dn][tc], pa[tc], oacc[dn]);
        __builtin_amdgcn_s_setprio(0);

        if (pf) {                              // write prefetched tile to other buffer
            int nx = cur ^ 1;
            *(s16x8*)&Ks[nx][srow * 72 + sc8] = kr0;
            *(s16x8*)&Ks[nx][(srow + 32) * 72 + sc8] = kr1;
            *(s16x8*)&Vs[nx][srow * 72 + sc8] = vr0;
            *(s16x8*)&Vs[nx][(srow + 32) * 72 + sc8] = vr1;
        }
        __syncthreads();                       // single barrier per k-tile
    }
    // fold l partials: 4 per-lane + the 4 lanes of each row (xor 16, 32)
    float rs = (l4[0] + l4[1]) + (l4[2] + l4[3]);
    rs += __shfl_xor(rs, 16, 64);
    rs += __shfl_xor(rs, 32, 64);
    int b = bh >> 4, hh = bh & 15;
    {
        float inv = 1.f / rs;
        int t = rbase + lr;
        size_t base = ((size_t)b * T_SEQ + t) * C_EMB + hh * HD;
#pragma unroll
        for (int dn = 0; dn < 4; ++dn) {
            f32x4 vv;
#pragma unroll
            for (int r = 0; r < 4; ++r) vv[r] = oacc[dn][r] * inv;
            *(u16x4*)(yab + base + dn * 16 + quad * 4) = pack4(vv);
        }
    }
}

// ---------------- k3: output projection (64x64 tiles, pipelined, dbuf) -----
// grid (16, 64): n0 = bx*64, m0 = by*64. 256 thr / 4 waves; wave (wr,wc)
// owns 32x32 (acc[2][2]). 4 blocks/CU x 4 waves = 16 waves/CU.
__global__ __launch_bounds__(256) void proj_k(const u16* __restrict__ ya, const u16* __restrict__ Wpb,
                                              const float* __restrict__ bias, float* __restrict__ out) {
    __shared__ u16 As[2][2048];               // [buf][64][32] linear (content swizzled)
    __shared__ u16 Bs[2][2048];
    int tid = threadIdx.x;
    int n0 = blockIdx.x * 64, m0 = blockIdx.y * 64;
    int w = tid >> 6, lane = tid & 63, lr = lane & 15, quad = lane >> 4;
    int wr = w >> 1, wc = w & 1;
    f32x4 acc[2][2] = {};
    int srow = tid >> 2;                                  // staging row 0..63
    int swc8 = (((tid & 3) ^ (srow & 3)) << 3);           // pre-swizzled src col (u16)
    int soff = tid * 8;                                   // linear LDS u16 offset
    int rc8 = ((quad ^ (lr & 3)) << 3);                   // swizzled fragment-read col

#define PRJ_STAGE(bufi, kc) do {                                                   \
        gload16(ya  + (size_t)(m0 + srow) * C_EMB + (kc) + swc8, &As[bufi][soff]); \
        gload16(Wpb + (size_t)(n0 + srow) * C_EMB + (kc) + swc8, &Bs[bufi][soff]); \
    } while (0)

    PRJ_STAGE(0, 0);
#pragma unroll 2
    for (int kt = 0; kt < 32; ++kt) {
        int cur = kt & 1;
        if (kt < 31) {
            PRJ_STAGE(cur ^ 1, (kt + 1) * 32);
            asm volatile("s_waitcnt vmcnt(2)" ::: "memory");
        } else {
            asm volatile("s_waitcnt vmcnt(0)" ::: "memory");
        }
        __builtin_amdgcn_s_barrier();
        asm volatile("" ::: "memory");
        s16x8 af[2], bf[2];
#pragma unroll
        for (int i = 0; i < 2; ++i)
            af[i] = *(const s16x8*)&As[cur][(wr * 32 + i * 16 + lr) * 32 + rc8];
#pragma unroll
        for (int j = 0; j < 2; ++j)
            bf[j] = *(const s16x8*)&Bs[cur][(wc * 32 + j * 16 + lr) * 32 + rc8];
#pragma unroll
        for (int i = 0; i < 2; ++i)
#pragma unroll
            for (int j = 0; j < 2; ++j) acc[i][j] = MFMA16(af[i], bf[j], acc[i][j]);
        asm volatile("" ::: "memory");
        __builtin_amdgcn_s_barrier();
    }
#undef PRJ_STAGE

    float bv[2];
#pragma unroll
    for (int j = 0; j < 2; ++j) bv[j] = bias[n0 + wc * 32 + j * 16 + lr];
#pragma unroll
    for (int i = 0; i < 2; ++i)
#pragma unroll
        for (int r = 0; r < 4; ++r) {
            int m = m0 + wr * 32 + i * 16 + quad * 4 + r;
#pragma unroll
            for (int j = 0; j < 2; ++j)
                out[(size_t)m * C_EMB + n0 + wc * 32 + j * 16 + lr] = acc[i][j][r] + bv[j];
        }
}

extern "C" void kernel_launch(void* const* d_in, const int* in_sizes, int n_in,
                              void* d_out, int out_size, void* d_ws, size_t ws_size,
                              hipStream_t stream) {
    // Inputs resolved BY ELEMENT COUNT (unique): x 4194304, W_attn 3145728,
    // b_attn 3072, W_proj 1048576, b_proj 1024. All fp32.
    const float *x = nullptr, *Wa = nullptr, *ba = nullptr, *Wp = nullptr, *bp = nullptr;
    for (int i = 0; i < n_in; ++i) {
        switch (in_sizes[i]) {
            case 4194304: x  = (const float*)d_in[i]; break;
            case 3145728: Wa = (const float*)d_in[i]; break;
            case 3072:    ba = (const float*)d_in[i]; break;
            case 1048576: Wp = (const float*)d_in[i]; break;
            case 1024:    bp = (const float*)d_in[i]; break;
            default: break;
        }
    }
    float* out = (float*)d_out;

    char* ws = (char*)d_ws;
    u16* qb     = (u16*)(ws);                    //  0.. 8 MiB  bf16 [B,H,T,D] (q*0.125*log2e)
    u16* kb     = (u16*)(ws + 8388608);          //  8..16 MiB  bf16 [B,H,T,D]
    u16* vt     = (u16*)(ws + 16777216);         // 16..24 MiB  bf16 [B,H,D,T]
    u16* yab    = (u16*)(ws + 25165824);         // 24..32 MiB  bf16 [B,T,C]
    float2* tab = (float2*)(ws + 33554432);      // 32..32.5 MiB
    u16* xb     = (u16*)(ws + 35651584);         // 34..42 MiB  bf16 [4096,1024]
    u16* Wab    = (u16*)(ws + 44040192);         // 42..48 MiB  bf16 [3072,1024]
    u16* Wpb    = (u16*)(ws + 50331648);         // 48..50 MiB  bf16 [1024,1024]

    prep_k<<<4352, 256, 0, stream>>>(x, Wa, Wp, xb, Wab, Wpb, tab);
    qkv_rope_k<<<dim3(24, 32), 256, 0, stream>>>(xb, Wab, ba, tab, qb, kb, vt);
    flash_k<<<dim3(32, 32), 256, 0, stream>>>(qb, kb, vt, yab);
    proj_k<<<dim3(16, 64), 256, 0, stream>>>(yab, Wpb, bp, out);
}

// Round 15
// 187.086 us; speedup vs baseline: 1.9757x; 1.0272x over previous
//
#include <hip/hip_runtime.h>

// B=2, T=2048, C=1024, H=16, D=64. Inputs fp32, OUTPUT fp32.
// Round 27 (post-mortem R26: flash re-anchored at 54.4us (tied best, 8
// variants all converge there); setprio neutral, kept. Freezing flash/qkv.
// Remaining visible defect: proj_k at BK=32 does only 4 MFMA per
// {stage,vmcnt,2xbarrier} period x32 periods — worst amortization in the
// pipeline):
//  - proj_k: BK 32 -> 64, double-buffered. Same grid (16,64), same 64x64
//    tile, same 8-slot XOR swizzle (slot=(ks>>3)+quad ^ lr&7, qkv-verified).
//    LDS 8->32KB (still 4 blocks/CU, 16 waves/CU). Periods 32->16, MFMA per
//    period 4->8. vmcnt(4) in-loop (4 loads in flight), 0 only at tail.
//  - prep_k / qkv_rope_k / flash_k unchanged from R26.
// MFMA 16x16x32_bf16 layouts (HW-verified): A: m=lane&15,k=quad*8+j;
// B: k=quad*8+j,n=lane&15; C/D: col=lane&15,row=quad*4+reg.
// MFMA 16x16x16_bf16 (HW-verified R17): A: m=lane&15,k=quad*4+j;
// B: k=quad*4+j,n=lane&15; C/D: col=lane&15,row=quad*4+reg.

typedef unsigned short u16;
typedef u16 u16x4 __attribute__((ext_vector_type(4)));
typedef u16 u16x8 __attribute__((ext_vector_type(8)));
typedef short s16x4 __attribute__((ext_vector_type(4)));
typedef short s16x8 __attribute__((ext_vector_type(8)));
typedef float f32x4 __attribute__((ext_vector_type(4)));

#define T_SEQ 2048
#define C_EMB 1024
#define NH 16
#define HD 64

#define MFMA16(a, b, c) __builtin_amdgcn_mfma_f32_16x16x32_bf16(a, b, c, 0, 0, 0)

__device__ __forceinline__ f32x4 MFMA16K16(s16x4 a, s16x4 b, f32x4 c) {
#if __has_builtin(__builtin_amdgcn_mfma_f32_16x16x16bf16_1k)
    return __builtin_amdgcn_mfma_f32_16x16x16bf16_1k(a, b, c, 0, 0, 0);
#else
    asm("v_mfma_f32_16x16x16_bf16 %0, %1, %2, %0" : "+v"(c) : "v"(a), "v"(b));
    return c;
#endif
}

__device__ __forceinline__ u16 f2bf(float f) {
    union { float f; unsigned int i; } x; x.f = f;
    unsigned int r = x.i + 0x7fffu + ((x.i >> 16) & 1u);
    return (u16)(r >> 16);
}
__device__ __forceinline__ u16x4 pack4(f32x4 v) {
    u16x4 o;
#pragma unroll
    for (int j = 0; j < 4; ++j) o[j] = f2bf(v[j]);
    return o;
}
// hot-loop pack: HW packed convert (RNE), 2 instr per 4 values -> s16x4 frag
__device__ __forceinline__ s16x4 pack4cvt_s(f32x4 v) {
    union { s16x4 h; unsigned int w[2]; } u;
    asm("v_cvt_pk_bf16_f32 %0, %1, %2" : "=v"(u.w[0]) : "v"(v[0]), "v"(v[1]));
    asm("v_cvt_pk_bf16_f32 %0, %1, %2" : "=v"(u.w[1]) : "v"(v[2]), "v"(v[3]));
    return u.h;
}
// async global->LDS, 16B per lane (dest must be wave-uniform base + lane*16)
__device__ __forceinline__ void gload16(const void* g, void* l) {
    __builtin_amdgcn_global_load_lds(
        (const __attribute__((address_space(1))) unsigned int*)g,
        (__attribute__((address_space(3))) unsigned int*)l, 16, 0, 0);
}

// ---------------- k0: merged prep (3x fp32->bf16 conv + rope tables) -------
// grid 4352: [0,2048) conv x; [2048,3584) conv Wa; [3584,4096) conv Wp;
// [4096,4352) rope tables. All sections exact-sized (no bounds checks).
__global__ __launch_bounds__(256) void prep_k(const float* __restrict__ x, const float* __restrict__ Wa,
                                              const float* __restrict__ Wp,
                                              u16* __restrict__ xb, u16* __restrict__ Wab,
                                              u16* __restrict__ Wpb, float2* __restrict__ tab) {
    int bid = blockIdx.x, tid = threadIdx.x;
    if (bid < 4096) {
        const float* src;
        u16* dst;
        int i;
        if (bid < 2048)      { src = x;  dst = xb;  i = bid * 256 + tid; }
        else if (bid < 3584) { src = Wa; dst = Wab; i = (bid - 2048) * 256 + tid; }
        else                 { src = Wp; dst = Wpb; i = (bid - 3584) * 256 + tid; }
        f32x4 a = ((const f32x4*)src)[i * 2];
        f32x4 b = ((const f32x4*)src)[i * 2 + 1];
        u16x8 o;
#pragma unroll
        for (int j = 0; j < 4; ++j) o[j] = f2bf(a[j]);
#pragma unroll
        for (int j = 0; j < 4; ++j) o[4 + j] = f2bf(b[j]);
        ((u16x8*)dst)[i] = o;
    } else {
        int idx = (bid - 4096) * 256 + tid;   // 65536 = T*32
        int t = idx >> 5, j = idx & 31;
        float inv = __builtin_exp2f(-0.41524101186092f * (float)j);  // 10000^(-j/32)
        float s_, c_;
        sincosf((float)t * inv, &s_, &c_);
        tab[idx] = make_float2(c_, s_);
    }
}

// ---------------- k1: QKV GEMM + RoPE (gload_lds, BK=32, 3-deep pipeline) --
// grid (24, 32): n0 = bx*128 (0..3071), m0 = by*128 (0..4095)
__global__ __launch_bounds__(256) void qkv_rope_k(const u16* __restrict__ xb, const u16* __restrict__ Wab,
                                                  const float* __restrict__ bias,
                                                  const float2* __restrict__ tab,
                                                  u16* __restrict__ qb, u16* __restrict__ kb,
                                                  u16* __restrict__ vt) {
    __shared__ u16 smem[24576];               // As[3][4096] | Bs[3][4096] = 48KB; Ct[17408] unions
    u16* As = smem;                           // [buf][128][32] linear (content swizzled)
    u16* Bs = smem + 12288;
    int tid = threadIdx.x;
    int n0 = blockIdx.x * 128, m0 = blockIdx.y * 128;
    int w = tid >> 6, lane = tid & 63, lr = lane & 15, quad = lane >> 4;
    int wr = w >> 1, wc = w & 1;
    f32x4 acc[4][4] = {};
    int srow = tid >> 2;                                  // staging row 0..63 (+64 second half)
    int swc8 = (((tid & 3) ^ (srow & 3)) << 3);           // pre-swizzled src col (u16)
    int soff = tid * 8;                                   // linear LDS u16 offset
    int rc8 = ((quad ^ (lr & 3)) << 3);                   // swizzled fragment-read col

#define QKV_STAGE(bufi, kc) do {                                                   \
        int _b = (bufi) * 4096;                                                    \
        gload16(xb  + (size_t)(m0 + srow) * C_EMB + (kc) + swc8,      &As[_b + soff]);        \
        gload16(xb  + (size_t)(m0 + 64 + srow) * C_EMB + (kc) + swc8, &As[_b + 2048 + soff]); \
        gload16(Wab + (size_t)(n0 + srow) * C_EMB + (kc) + swc8,      &Bs[_b + soff]);        \
        gload16(Wab + (size_t)(n0 + 64 + srow) * C_EMB + (kc) + swc8, &Bs[_b + 2048 + soff]); \
    } while (0)

    QKV_STAGE(0, 0);
    QKV_STAGE(1, 32);
    int cur = 0;
    for (int kt = 0; kt < 32; ++kt) {
        if (kt < 30) {
            int nb = cur + 2; if (nb >= 3) nb -= 3;
            QKV_STAGE(nb, (kt + 2) * 32);
            asm volatile("s_waitcnt vmcnt(8)" ::: "memory");   // tile-kt loads done
        } else if (kt == 30) {
            asm volatile("s_waitcnt vmcnt(4)" ::: "memory");
        } else {
            asm volatile("s_waitcnt vmcnt(0)" ::: "memory");
        }
        __builtin_amdgcn_s_barrier();
        asm volatile("" ::: "memory");
        int cb = cur * 4096;
        s16x8 af[4], bf[4];
#pragma unroll
        for (int i = 0; i < 4; ++i)
            af[i] = *(const s16x8*)&As[cb + (wr * 64 + i * 16 + lr) * 32 + rc8];
#pragma unroll
        for (int j = 0; j < 4; ++j)
            bf[j] = *(const s16x8*)&Bs[cb + (wc * 64 + j * 16 + lr) * 32 + rc8];
#pragma unroll
        for (int i = 0; i < 4; ++i)
#pragma unroll
            for (int j = 0; j < 4; ++j) acc[i][j] = MFMA16(af[i], bf[j], acc[i][j]);
        asm volatile("" ::: "memory");
        __builtin_amdgcn_s_barrier();
        cur = cur + 1; if (cur >= 3) cur -= 3;
    }
#undef QKV_STAGE

    int sec = n0 >> 10;                       // 0=q 1=k 2=v (blocks never straddle)
    float bv[4];
#pragma unroll
    for (int j = 0; j < 4; ++j) bv[j] = bias[n0 + wc * 64 + j * 16 + lr];

    int h0 = (n0 & 1023) >> 6;
    int b = m0 >> 11, tbase = m0 & 2047;
    if (sec == 2) {
        // C tile (+bias) -> LDS [d][m] (136-padded) -> coalesced 16B
        // transposed stores to vt[((b*16+h)*64+d)*2048 + t].
        u16* Ct = smem;                        // 128 x 136 u16 = 34816 B
#pragma unroll
        for (int i = 0; i < 4; ++i)
#pragma unroll
            for (int j = 0; j < 4; ++j) {
                f32x4 vv;
#pragma unroll
                for (int r = 0; r < 4; ++r) vv[r] = acc[i][j][r] + bv[j];
                int d = wc * 64 + j * 16 + lr;
                int m4 = wr * 64 + i * 16 + quad * 4;
                *(u16x4*)&Ct[d * 136 + m4] = pack4(vv);
            }
        __syncthreads();
        size_t hb = (size_t)(b * NH);
#pragma unroll
        for (int p = 0; p < 8; ++p) {
            int idx = p * 256 + tid;
            int d = idx >> 4, mc = (idx & 15) << 3;
            s16x8 vdat = *(const s16x8*)&Ct[d * 136 + mc];
            int h = h0 + (d >> 6), dd = d & 63;
            *(s16x8*)(vt + ((hb + h) * HD + dd) * T_SEQ + tbase + mc) = vdat;
        }
    } else {
        // q/k: RoPE in-register, stage [m][n] in LDS, coalesced b128 stores.
        u16* dst = (sec == 0) ? qb : kb;
        // fold 1/sqrt(D) AND log2(e) into q so flash softmax is native base-2:
        float qs = (sec == 0) ? 0.18033688011112043f : 1.0f;
        u16* Ct = smem;                        // 128 x 136 u16
        __syncthreads();                       // all frag reads done before overwrite
#pragma unroll
        for (int i = 0; i < 4; ++i)
#pragma unroll
            for (int r = 0; r < 4; ++r) {
                int mrow = wr * 64 + i * 16 + quad * 4 + r;
                int t = (m0 + mrow) & 2047;
#pragma unroll
                for (int j = 0; j < 2; ++j) {
                    int d1 = j * 16 + lr;                 // 0..31; partner +32 in tile j+2
                    float2 cs = tab[t * 32 + d1];
                    float v1 = acc[i][j][r] + bv[j];
                    float v2 = acc[i][j + 2][r] + bv[j + 2];
                    int n1 = wc * 64 + j * 16 + lr;
                    Ct[mrow * 136 + n1]      = f2bf((v1 * cs.x - v2 * cs.y) * qs);
                    Ct[mrow * 136 + n1 + 32] = f2bf((v2 * cs.x + v1 * cs.y) * qs);
                }
            }
        __syncthreads();
#pragma unroll
        for (int p = 0; p < 8; ++p) {
            int idx = p * 256 + tid;              // 128 rows x 16 chunks of 8 u16
            int mrow = idx >> 4, c = idx & 15;
            s16x8 vdat = *(const s16x8*)&Ct[mrow * 136 + c * 8];
            int h = h0 + (c >> 3), dd = (c & 7) << 3;
            *(s16x8*)(dst + ((size_t)(b * NH + h) * T_SEQ + tbase + mrow) * HD + dd) = vdat;
        }
    }
}

// ---------------- k2: flash attention (64-row Q tile, 4 blocks/CU) ---------
// grid (32, 32), 256 threads / 4 waves / 1 strip each. qt = q-tile of 64
// rows; wave w owns rows [qt*64+16w, +16). 1024 blocks = 4 blocks/CU
// (LDS 36.9KB). Every strip active in every tile; mask only on kt==qt.
// S^T: elem (k'=k0+tc*16+quad*4+r, q=rbase+lr). PV: 16x16x16, P in regs.
// Double-buffered K/V LDS, one barrier per k-tile. T5 setprio around MFMAs.
__global__ __launch_bounds__(256, 4) void flash_k(const u16* __restrict__ qb, const u16* __restrict__ kb,
                                                  const u16* __restrict__ vt, u16* __restrict__ yab) {
    __shared__ u16 Ks[2][64 * 72];
    __shared__ u16 Vs[2][64 * 72];
    int tid = threadIdx.x;
    int bx = blockIdx.x, by = blockIdx.y;
    int qt = (by < 16) ? (31 - bx) : bx;      // complementary pairing for balance
    int bh = by;
    int w = tid >> 6, lane = tid & 63, lr = lane & 15, quad = lane >> 4;
    int q0 = qt * 64;
    const u16* qh = qb + (size_t)bh * T_SEQ * HD;
    const u16* kh = kb + (size_t)bh * T_SEQ * HD;
    const u16* vh = vt + (size_t)bh * HD * T_SEQ;

    int rbase = q0 + w * 16;                  // this wave's strip

    s16x8 aq[2];                              // B-frag of Q (n=q-row=lr, k=d)
#pragma unroll
    for (int ks = 0; ks < 2; ++ks)
        aq[ks] = *(const s16x8*)(qh + (size_t)(rbase + lr) * HD + ks * 32 + quad * 8);

    int srow = tid >> 3, sc8 = (tid & 7) << 3;   // staging: rows srow, srow+32

    float m_i = -1e30f;
    f32x4 l4 = {0.f, 0.f, 0.f, 0.f};          // per-lane l partials
    f32x4 oacc[4] = {};                       // O^T: elem (d=dn*16+quad*4+r, q=lr)

    int ktmax = qt;
    {   // prologue: stage tile 0 into buffer 0 (2 K-rows + 2 V-rows / thread)
        s16x8 ka = *(const s16x8*)(kh + (size_t)srow * HD + sc8);
        s16x8 kb2 = *(const s16x8*)(kh + (size_t)(srow + 32) * HD + sc8);
        s16x8 va = *(const s16x8*)(vh + (size_t)srow * T_SEQ + sc8);
        s16x8 vb = *(const s16x8*)(vh + (size_t)(srow + 32) * T_SEQ + sc8);
        *(s16x8*)&Ks[0][srow * 72 + sc8] = ka;
        *(s16x8*)&Ks[0][(srow + 32) * 72 + sc8] = kb2;
        *(s16x8*)&Vs[0][srow * 72 + sc8] = va;
        *(s16x8*)&Vs[0][(srow + 32) * 72 + sc8] = vb;
    }
    __syncthreads();

    for (int kt = 0; kt <= ktmax; ++kt) {
        int cur = kt & 1;
        int k0 = kt * 64;
        bool pf = kt < ktmax;
        s16x8 kr0, kr1, vr0, vr1;             // next-tile prefetch registers
        if (pf) {
            int kn = k0 + 64;
            kr0 = *(const s16x8*)(kh + (size_t)(kn + srow) * HD + sc8);
            kr1 = *(const s16x8*)(kh + (size_t)(kn + srow + 32) * HD + sc8);
            vr0 = *(const s16x8*)(vh + (size_t)srow * T_SEQ + kn + sc8);
            vr1 = *(const s16x8*)(vh + (size_t)(srow + 32) * T_SEQ + kn + sc8);
        }
        const u16* Kc = Ks[cur];
        const u16* Vc = Vs[cur];

        // fragments (all strips active every tile in the 64-row form)
        s16x8 ak[2][4];                       // K frag (m=k-row=lr, k=d)
#pragma unroll
        for (int ks = 0; ks < 2; ++ks)
#pragma unroll
            for (int tc = 0; tc < 4; ++tc)
                ak[ks][tc] = *(const s16x8*)&Kc[(tc * 16 + lr) * 72 + ks * 32 + quad * 8];
        s16x4 av[4][4];                       // V^T frag (m=d=dn*16+lr, k=tc*16+quad*4+j)
#pragma unroll
        for (int dn = 0; dn < 4; ++dn) {
            const u16* vrow = &Vc[(dn * 16 + lr) * 72 + quad * 4];
#pragma unroll
            for (int tc = 0; tc < 4; ++tc)
                av[dn][tc] = *(const s16x4*)(vrow + tc * 16);
        }
        f32x4 sacc[4] = {};
        __builtin_amdgcn_s_setprio(1);        // T5: favor MFMA wave
#pragma unroll
        for (int ks = 0; ks < 2; ++ks)
#pragma unroll
            for (int tc = 0; tc < 4; ++tc) sacc[tc] = MFMA16(ak[ks][tc], aq[ks], sacc[tc]);
        __builtin_amdgcn_s_setprio(0);
        if (kt == ktmax) {                    // diagonal tile: causal mask
#pragma unroll
            for (int tc = 0; tc < 4; ++tc)
#pragma unroll
                for (int r = 0; r < 4; ++r)
                    if (k0 + tc * 16 + quad * 4 + r > rbase + lr) sacc[tc][r] = -1e30f;
        }
        // per-lane local max; __all == row-max guard
        f32x4 mv = sacc[0];
#pragma unroll
        for (int tc = 1; tc < 4; ++tc)
#pragma unroll
            for (int r = 0; r < 4; ++r) mv[r] = fmaxf(mv[r], sacc[tc][r]);
        float loc = fmaxf(fmaxf(mv[0], mv[1]), fmaxf(mv[2], mv[3]));
        bool need = !__all(loc <= m_i + 8.0f);   // defer-max (T13, THR=8)
        float alpha = 1.0f;
        if (need) {                            // rare: full cross-lane max
            float mx = fmaxf(loc, __shfl_xor(loc, 16, 64));
            mx = fmaxf(mx, __shfl_xor(mx, 32, 64));
            float mn = fmaxf(m_i, mx);
            alpha = __builtin_exp2f(m_i - mn);
            m_i = mn;
#pragma unroll
            for (int r = 0; r < 4; ++r) l4[r] *= alpha;
        }
        float mnow = m_i;
#pragma unroll
        for (int tc = 0; tc < 4; ++tc)
#pragma unroll
            for (int r = 0; r < 4; ++r) {
                float p = __builtin_exp2f(sacc[tc][r] - mnow);
                sacc[tc][r] = p;
                l4[r] += p;                    // per-lane partial; folded at end
            }
        // P in registers: pack4cvt(sacc[tc]) IS the 16x16x16 B-frag
        s16x4 pa[4];
#pragma unroll
        for (int tc = 0; tc < 4; ++tc) pa[tc] = pack4cvt_s(sacc[tc]);
        if (need) {
#pragma unroll
            for (int dn = 0; dn < 4; ++dn)
#pragma unroll
                for (int r = 0; r < 4; ++r) oacc[dn][r] *= alpha;
        }
        __builtin_amdgcn_s_setprio(1);        // T5: favor MFMA wave
#pragma unroll
        for (int dn = 0; dn < 4; ++dn)
#pragma unroll
            for (int tc = 0; tc < 4; ++tc)
                oacc[dn] = MFMA16K16(av[dn][tc], pa[tc], oacc[dn]);
        __builtin_amdgcn_s_setprio(0);

        if (pf) {                              // write prefetched tile to other buffer
            int nx = cur ^ 1;
            *(s16x8*)&Ks[nx][srow * 72 + sc8] = kr0;
            *(s16x8*)&Ks[nx][(srow + 32) * 72 + sc8] = kr1;
            *(s16x8*)&Vs[nx][srow * 72 + sc8] = vr0;
            *(s16x8*)&Vs[nx][(srow + 32) * 72 + sc8] = vr1;
        }
        __syncthreads();                       // single barrier per k-tile
    }
    // fold l partials: 4 per-lane + the 4 lanes of each row (xor 16, 32)
    float rs = (l4[0] + l4[1]) + (l4[2] + l4[3]);
    rs += __shfl_xor(rs, 16, 64);
    rs += __shfl_xor(rs, 32, 64);
    int b = bh >> 4, hh = bh & 15;
    {
        float inv = 1.f / rs;
        int t = rbase + lr;
        size_t base = ((size_t)b * T_SEQ + t) * C_EMB + hh * HD;
#pragma unroll
        for (int dn = 0; dn < 4; ++dn) {
            f32x4 vv;
#pragma unroll
            for (int r = 0; r < 4; ++r) vv[r] = oacc[dn][r] * inv;
            *(u16x4*)(yab + base + dn * 16 + quad * 4) = pack4(vv);
        }
    }
}

// ---------------- k3: output projection (64x64 tiles, BK=64, dbuf) ---------
// grid (16, 64): n0 = bx*64, m0 = by*64. 256 thr / 4 waves; wave (wr,wc)
// owns 32x32 (acc[2][2]). LDS 32KB -> 4 blocks/CU x 4 waves = 16 waves/CU.
// 16 K-iters (was 32): per iter 4 gload16/thread, 8 b128 frag reads,
// 8 MFMA/wave, vmcnt(4) + 2 barriers. Same 8-slot XOR swizzle as qkv:
// LDS[row][s] = G[row][s ^ (row&7)]; read slot = ((ks>>3)+quad) ^ (lr&7).
__global__ __launch_bounds__(256) void proj_k(const u16* __restrict__ ya, const u16* __restrict__ Wpb,
                                              const float* __restrict__ bias, float* __restrict__ out) {
    __shared__ u16 As[2][4096];               // [buf][64][64] linear (content swizzled)
    __shared__ u16 Bs[2][4096];
    int tid = threadIdx.x;
    int n0 = blockIdx.x * 64, m0 = blockIdx.y * 64;
    int w = tid >> 6, lane = tid & 63, lr = lane & 15, quad = lane >> 4;
    int wr = w >> 1, wc = w & 1;
    f32x4 acc[2][2] = {};
    int srow = tid >> 3;                                  // staging row 0..31 (+32 second chunk)
    int swc8 = (((tid & 7) ^ (srow & 7)) << 3);           // pre-swizzled src col (u16)
    int soff = tid * 8;                                   // linear LDS u16 offset
    int lrx = lr & 7;                                     // fragment-read XOR key

#define PRJ_STAGE(bufi, kc) do {                                                     \
        gload16(ya  + (size_t)(m0 + srow) * C_EMB + (kc) + swc8,      &As[bufi][soff]);        \
        gload16(ya  + (size_t)(m0 + 32 + srow) * C_EMB + (kc) + swc8, &As[bufi][2048 + soff]); \
        gload16(Wpb + (size_t)(n0 + srow) * C_EMB + (kc) + swc8,      &Bs[bufi][soff]);        \
        gload16(Wpb + (size_t)(n0 + 32 + srow) * C_EMB + (kc) + swc8, &Bs[bufi][2048 + soff]); \
    } while (0)

    PRJ_STAGE(0, 0);
#pragma unroll 2
    for (int kt = 0; kt < 16; ++kt) {
        int cur = kt & 1;
        if (kt < 15) {
            PRJ_STAGE(cur ^ 1, (kt + 1) * 64);
            asm volatile("s_waitcnt vmcnt(4)" ::: "memory");
        } else {
            asm volatile("s_waitcnt vmcnt(0)" ::: "memory");
        }
        __builtin_amdgcn_s_barrier();
        asm volatile("" ::: "memory");
#pragma unroll
        for (int ks = 0; ks < 64; ks += 32) {
            int slot = (ks >> 3) + quad;                   // 0..7
            int rc8 = ((slot ^ lrx) << 3);                 // swizzled read col (u16)
            s16x8 af[2], bf[2];
#pragma unroll
            for (int i = 0; i < 2; ++i)
                af[i] = *(const s16x8*)&As[cur][(wr * 32 + i * 16 + lr) * 64 + rc8];
#pragma unroll
            for (int j = 0; j < 2; ++j)
                bf[j] = *(const s16x8*)&Bs[cur][(wc * 32 + j * 16 + lr) * 64 + rc8];
#pragma unroll
            for (int i = 0; i < 2; ++i)
#pragma unroll
                for (int j = 0; j < 2; ++j) acc[i][j] = MFMA16(af[i], bf[j], acc[i][j]);
        }
        asm volatile("" ::: "memory");
        __builtin_amdgcn_s_barrier();
    }
#undef PRJ_STAGE

    float bv[2];
#pragma unroll
    for (int j = 0; j < 2; ++j) bv[j] = bias[n0 + wc * 32 + j * 16 + lr];
#pragma unroll
    for (int i = 0; i < 2; ++i)
#pragma unroll
        for (int r = 0; r < 4; ++r) {
            int m = m0 + wr * 32 + i * 16 + quad * 4 + r;
#pragma unroll
            for (int j = 0; j < 2; ++j)
                out[(size_t)m * C_EMB + n0 + wc * 32 + j * 16 + lr] = acc[i][j][r] + bv[j];
        }
}

extern "C" void kernel_launch(void* const* d_in, const int* in_sizes, int n_in,
                              void* d_out, int out_size, void* d_ws, size_t ws_size,
                              hipStream_t stream) {
    // Inputs resolved BY ELEMENT COUNT (unique): x 4194304, W_attn 3145728,
    // b_attn 3072, W_proj 1048576, b_proj 1024. All fp32.
    const float *x = nullptr, *Wa = nullptr, *ba = nullptr, *Wp = nullptr, *bp = nullptr;
    for (int i = 0; i < n_in; ++i) {
        switch (in_sizes[i]) {
            case 4194304: x  = (const float*)d_in[i]; break;
            case 3145728: Wa = (const float*)d_in[i]; break;
            case 3072:    ba = (const float*)d_in[i]; break;
            case 1048576: Wp = (const float*)d_in[i]; break;
            case 1024:    bp = (const float*)d_in[i]; break;
            default: break;
        }
    }
    float* out = (float*)d_out;

    char* ws = (char*)d_ws;
    u16* qb     = (u16*)(ws);                    //  0.. 8 MiB  bf16 [B,H,T,D] (q*0.125*log2e)
    u16* kb     = (u16*)(ws + 8388608);          //  8..16 MiB  bf16 [B,H,T,D]
    u16* vt     = (u16*)(ws + 16777216);         // 16..24 MiB  bf16 [B,H,D,T]
    u16* yab    = (u16*)(ws + 25165824);         // 24..32 MiB  bf16 [B,T,C]
    float2* tab = (float2*)(ws + 33554432);      // 32..32.5 MiB
    u16* xb     = (u16*)(ws + 35651584);         // 34..42 MiB  bf16 [4096,1024]
    u16* Wab    = (u16*)(ws + 44040192);         // 42..48 MiB  bf16 [3072,1024]
    u16* Wpb    = (u16*)(ws + 50331648);         // 48..50 MiB  bf16 [1024,1024]

    prep_k<<<4352, 256, 0, stream>>>(x, Wa, Wp, xb, Wab, Wpb, tab);
    qkv_rope_k<<<dim3(24, 32), 256, 0, stream>>>(xb, Wab, ba, tab, qb, kb, vt);
    flash_k<<<dim3(32, 32), 256, 0, stream>>>(qb, kb, vt, yab);
    proj_k<<<dim3(16, 64), 256, 0, stream>>>(yab, Wpb, bp, out);
}

// Round 16
// 183.954 us; speedup vs baseline: 2.0094x; 1.0170x over previous
//
#include <hip/hip_runtime.h>

// B=2, T=2048, C=1024, H=16, D=64. Inputs fp32, OUTPUT fp32.
// Round 28 (post-mortem R27: proj BK=64 paid (-5.1us). flash stuck at 54.4
// with deterministic 6.49M LDS bank conflicts; analysis: 72-pad (144B row
// stride) makes the av b64 reads bank-UNEVEN (start = 4lr+2quad+8tc mod 32
// collides) while ak/writes are balanced. LDS pipe ~28us of the 54.4 wall):
//  - flash_k: K/V LDS tiles 72-pad -> [64][64] LINEAR + 8-slot XOR swizzle
//    (slot ^= row&7; qkv/proj-proven family). Reg-staged writes swizzle the
//    LDS address; ak reads slot=(ks*4+quad)^lr&7; av reads
//    slot=(2tc+(quad>>1))^lr&7 + (quad&1)*4 u16. All three access families
//    provably bank-uniform. LDS 36.9 -> 32KB. Rest identical to R27.
//  - prep_k / qkv_rope_k / proj_k unchanged.
// MFMA 16x16x32_bf16 layouts (HW-verified): A: m=lane&15,k=quad*8+j;
// B: k=quad*8+j,n=lane&15; C/D: col=lane&15,row=quad*4+reg.
// MFMA 16x16x16_bf16 (HW-verified R17): A: m=lane&15,k=quad*4+j;
// B: k=quad*4+j,n=lane&15; C/D: col=lane&15,row=quad*4+reg.

typedef unsigned short u16;
typedef u16 u16x4 __attribute__((ext_vector_type(4)));
typedef u16 u16x8 __attribute__((ext_vector_type(8)));
typedef short s16x4 __attribute__((ext_vector_type(4)));
typedef short s16x8 __attribute__((ext_vector_type(8)));
typedef float f32x4 __attribute__((ext_vector_type(4)));

#define T_SEQ 2048
#define C_EMB 1024
#define NH 16
#define HD 64

#define MFMA16(a, b, c) __builtin_amdgcn_mfma_f32_16x16x32_bf16(a, b, c, 0, 0, 0)

__device__ __forceinline__ f32x4 MFMA16K16(s16x4 a, s16x4 b, f32x4 c) {
#if __has_builtin(__builtin_amdgcn_mfma_f32_16x16x16bf16_1k)
    return __builtin_amdgcn_mfma_f32_16x16x16bf16_1k(a, b, c, 0, 0, 0);
#else
    asm("v_mfma_f32_16x16x16_bf16 %0, %1, %2, %0" : "+v"(c) : "v"(a), "v"(b));
    return c;
#endif
}

__device__ __forceinline__ u16 f2bf(float f) {
    union { float f; unsigned int i; } x; x.f = f;
    unsigned int r = x.i + 0x7fffu + ((x.i >> 16) & 1u);
    return (u16)(r >> 16);
}
__device__ __forceinline__ u16x4 pack4(f32x4 v) {
    u16x4 o;
#pragma unroll
    for (int j = 0; j < 4; ++j) o[j] = f2bf(v[j]);
    return o;
}
// hot-loop pack: HW packed convert (RNE), 2 instr per 4 values -> s16x4 frag
__device__ __forceinline__ s16x4 pack4cvt_s(f32x4 v) {
    union { s16x4 h; unsigned int w[2]; } u;
    asm("v_cvt_pk_bf16_f32 %0, %1, %2" : "=v"(u.w[0]) : "v"(v[0]), "v"(v[1]));
    asm("v_cvt_pk_bf16_f32 %0, %1, %2" : "=v"(u.w[1]) : "v"(v[2]), "v"(v[3]));
    return u.h;
}
// async global->LDS, 16B per lane (dest must be wave-uniform base + lane*16)
__device__ __forceinline__ void gload16(const void* g, void* l) {
    __builtin_amdgcn_global_load_lds(
        (const __attribute__((address_space(1))) unsigned int*)g,
        (__attribute__((address_space(3))) unsigned int*)l, 16, 0, 0);
}

// ---------------- k0: merged prep (3x fp32->bf16 conv + rope tables) -------
// grid 4352: [0,2048) conv x; [2048,3584) conv Wa; [3584,4096) conv Wp;
// [4096,4352) rope tables. All sections exact-sized (no bounds checks).
__global__ __launch_bounds__(256) void prep_k(const float* __restrict__ x, const float* __restrict__ Wa,
                                              const float* __restrict__ Wp,
                                              u16* __restrict__ xb, u16* __restrict__ Wab,
                                              u16* __restrict__ Wpb, float2* __restrict__ tab) {
    int bid = blockIdx.x, tid = threadIdx.x;
    if (bid < 4096) {
        const float* src;
        u16* dst;
        int i;
        if (bid < 2048)      { src = x;  dst = xb;  i = bid * 256 + tid; }
        else if (bid < 3584) { src = Wa; dst = Wab; i = (bid - 2048) * 256 + tid; }
        else                 { src = Wp; dst = Wpb; i = (bid - 3584) * 256 + tid; }
        f32x4 a = ((const f32x4*)src)[i * 2];
        f32x4 b = ((const f32x4*)src)[i * 2 + 1];
        u16x8 o;
#pragma unroll
        for (int j = 0; j < 4; ++j) o[j] = f2bf(a[j]);
#pragma unroll
        for (int j = 0; j < 4; ++j) o[4 + j] = f2bf(b[j]);
        ((u16x8*)dst)[i] = o;
    } else {
        int idx = (bid - 4096) * 256 + tid;   // 65536 = T*32
        int t = idx >> 5, j = idx & 31;
        float inv = __builtin_exp2f(-0.41524101186092f * (float)j);  // 10000^(-j/32)
        float s_, c_;
        sincosf((float)t * inv, &s_, &c_);
        tab[idx] = make_float2(c_, s_);
    }
}

// ---------------- k1: QKV GEMM + RoPE (gload_lds, BK=32, 3-deep pipeline) --
// grid (24, 32): n0 = bx*128 (0..3071), m0 = by*128 (0..4095)
__global__ __launch_bounds__(256) void qkv_rope_k(const u16* __restrict__ xb, const u16* __restrict__ Wab,
                                                  const float* __restrict__ bias,
                                                  const float2* __restrict__ tab,
                                                  u16* __restrict__ qb, u16* __restrict__ kb,
                                                  u16* __restrict__ vt) {
    __shared__ u16 smem[24576];               // As[3][4096] | Bs[3][4096] = 48KB; Ct[17408] unions
    u16* As = smem;                           // [buf][128][32] linear (content swizzled)
    u16* Bs = smem + 12288;
    int tid = threadIdx.x;
    int n0 = blockIdx.x * 128, m0 = blockIdx.y * 128;
    int w = tid >> 6, lane = tid & 63, lr = lane & 15, quad = lane >> 4;
    int wr = w >> 1, wc = w & 1;
    f32x4 acc[4][4] = {};
    int srow = tid >> 2;                                  // staging row 0..63 (+64 second half)
    int swc8 = (((tid & 3) ^ (srow & 3)) << 3);           // pre-swizzled src col (u16)
    int soff = tid * 8;                                   // linear LDS u16 offset
    int rc8 = ((quad ^ (lr & 3)) << 3);                   // swizzled fragment-read col

#define QKV_STAGE(bufi, kc) do {                                                   \
        int _b = (bufi) * 4096;                                                    \
        gload16(xb  + (size_t)(m0 + srow) * C_EMB + (kc) + swc8,      &As[_b + soff]);        \
        gload16(xb  + (size_t)(m0 + 64 + srow) * C_EMB + (kc) + swc8, &As[_b + 2048 + soff]); \
        gload16(Wab + (size_t)(n0 + srow) * C_EMB + (kc) + swc8,      &Bs[_b + soff]);        \
        gload16(Wab + (size_t)(n0 + 64 + srow) * C_EMB + (kc) + swc8, &Bs[_b + 2048 + soff]); \
    } while (0)

    QKV_STAGE(0, 0);
    QKV_STAGE(1, 32);
    int cur = 0;
    for (int kt = 0; kt < 32; ++kt) {
        if (kt < 30) {
            int nb = cur + 2; if (nb >= 3) nb -= 3;
            QKV_STAGE(nb, (kt + 2) * 32);
            asm volatile("s_waitcnt vmcnt(8)" ::: "memory");   // tile-kt loads done
        } else if (kt == 30) {
            asm volatile("s_waitcnt vmcnt(4)" ::: "memory");
        } else {
            asm volatile("s_waitcnt vmcnt(0)" ::: "memory");
        }
        __builtin_amdgcn_s_barrier();
        asm volatile("" ::: "memory");
        int cb = cur * 4096;
        s16x8 af[4], bf[4];
#pragma unroll
        for (int i = 0; i < 4; ++i)
            af[i] = *(const s16x8*)&As[cb + (wr * 64 + i * 16 + lr) * 32 + rc8];
#pragma unroll
        for (int j = 0; j < 4; ++j)
            bf[j] = *(const s16x8*)&Bs[cb + (wc * 64 + j * 16 + lr) * 32 + rc8];
#pragma unroll
        for (int i = 0; i < 4; ++i)
#pragma unroll
            for (int j = 0; j < 4; ++j) acc[i][j] = MFMA16(af[i], bf[j], acc[i][j]);
        asm volatile("" ::: "memory");
        __builtin_amdgcn_s_barrier();
        cur = cur + 1; if (cur >= 3) cur -= 3;
    }
#undef QKV_STAGE

    int sec = n0 >> 10;                       // 0=q 1=k 2=v (blocks never straddle)
    float bv[4];
#pragma unroll
    for (int j = 0; j < 4; ++j) bv[j] = bias[n0 + wc * 64 + j * 16 + lr];

    int h0 = (n0 & 1023) >> 6;
    int b = m0 >> 11, tbase = m0 & 2047;
    if (sec == 2) {
        // C tile (+bias) -> LDS [d][m] (136-padded) -> coalesced 16B
        // transposed stores to vt[((b*16+h)*64+d)*2048 + t].
        u16* Ct = smem;                        // 128 x 136 u16 = 34816 B
#pragma unroll
        for (int i = 0; i < 4; ++i)
#pragma unroll
            for (int j = 0; j < 4; ++j) {
                f32x4 vv;
#pragma unroll
                for (int r = 0; r < 4; ++r) vv[r] = acc[i][j][r] + bv[j];
                int d = wc * 64 + j * 16 + lr;
                int m4 = wr * 64 + i * 16 + quad * 4;
                *(u16x4*)&Ct[d * 136 + m4] = pack4(vv);
            }
        __syncthreads();
        size_t hb = (size_t)(b * NH);
#pragma unroll
        for (int p = 0; p < 8; ++p) {
            int idx = p * 256 + tid;
            int d = idx >> 4, mc = (idx & 15) << 3;
            s16x8 vdat = *(const s16x8*)&Ct[d * 136 + mc];
            int h = h0 + (d >> 6), dd = d & 63;
            *(s16x8*)(vt + ((hb + h) * HD + dd) * T_SEQ + tbase + mc) = vdat;
        }
    } else {
        // q/k: RoPE in-register, stage [m][n] in LDS, coalesced b128 stores.
        u16* dst = (sec == 0) ? qb : kb;
        // fold 1/sqrt(D) AND log2(e) into q so flash softmax is native base-2:
        float qs = (sec == 0) ? 0.18033688011112043f : 1.0f;
        u16* Ct = smem;                        // 128 x 136 u16
        __syncthreads();                       // all frag reads done before overwrite
#pragma unroll
        for (int i = 0; i < 4; ++i)
#pragma unroll
            for (int r = 0; r < 4; ++r) {
                int mrow = wr * 64 + i * 16 + quad * 4 + r;
                int t = (m0 + mrow) & 2047;
#pragma unroll
                for (int j = 0; j < 2; ++j) {
                    int d1 = j * 16 + lr;                 // 0..31; partner +32 in tile j+2
                    float2 cs = tab[t * 32 + d1];
                    float v1 = acc[i][j][r] + bv[j];
                    float v2 = acc[i][j + 2][r] + bv[j + 2];
                    int n1 = wc * 64 + j * 16 + lr;
                    Ct[mrow * 136 + n1]      = f2bf((v1 * cs.x - v2 * cs.y) * qs);
                    Ct[mrow * 136 + n1 + 32] = f2bf((v2 * cs.x + v1 * cs.y) * qs);
                }
            }
        __syncthreads();
#pragma unroll
        for (int p = 0; p < 8; ++p) {
            int idx = p * 256 + tid;              // 128 rows x 16 chunks of 8 u16
            int mrow = idx >> 4, c = idx & 15;
            s16x8 vdat = *(const s16x8*)&Ct[mrow * 136 + c * 8];
            int h = h0 + (c >> 3), dd = (c & 7) << 3;
            *(s16x8*)(dst + ((size_t)(b * NH + h) * T_SEQ + tbase + mrow) * HD + dd) = vdat;
        }
    }
}

// ---------------- k2: flash attention (64-row Q tile, XOR-swizzled LDS) ----
// grid (32, 32), 256 threads / 4 waves / 1 strip each. qt = q-tile of 64
// rows; wave w owns rows [qt*64+16w, +16). 1024 blocks = whole grid
// co-resident at 4 blocks/CU (LDS 32KB). Mask only on kt==qt.
// K/V LDS: [64][64] linear, 8-slot XOR swizzle LDS[row][s]=G[row][s^(row&7)]
// (reg-staged writes swizzle the LDS addr). ak slot=(ks*4+quad)^(lr&7);
// av slot=(2tc+(quad>>1))^(lr&7), +4 u16 if quad odd. All bank-uniform.
// S^T: elem (k'=k0+tc*16+quad*4+r, q=rbase+lr). PV: 16x16x16, P in regs.
// Double-buffered K/V, one barrier per k-tile. T5 setprio around MFMAs.
__global__ __launch_bounds__(256, 4) void flash_k(const u16* __restrict__ qb, const u16* __restrict__ kb,
                                                  const u16* __restrict__ vt, u16* __restrict__ yab) {
    __shared__ u16 Ks[2][64 * 64];
    __shared__ u16 Vs[2][64 * 64];
    int tid = threadIdx.x;
    int bx = blockIdx.x, by = blockIdx.y;
    int qt = (by < 16) ? (31 - bx) : bx;      // complementary pairing for balance
    int bh = by;
    int w = tid >> 6, lane = tid & 63, lr = lane & 15, quad = lane >> 4;
    int q0 = qt * 64;
    const u16* qh = qb + (size_t)bh * T_SEQ * HD;
    const u16* kh = kb + (size_t)bh * T_SEQ * HD;
    const u16* vh = vt + (size_t)bh * HD * T_SEQ;

    int rbase = q0 + w * 16;                  // this wave's strip

    s16x8 aq[2];                              // B-frag of Q (n=q-row=lr, k=d)
#pragma unroll
    for (int ks = 0; ks < 2; ++ks)
        aq[ks] = *(const s16x8*)(qh + (size_t)(rbase + lr) * HD + ks * 32 + quad * 8);

    int srow = tid >> 3, sc8 = (tid & 7) << 3;       // staging: rows srow, srow+32
    int swsl = (((tid & 7) ^ (srow & 7)) << 3);      // swizzled LDS write col (u16)
    int lrx8 = (lr & 7) << 3;                        // fragment-read XOR key (u16 units)

    float m_i = -1e30f;
    f32x4 l4 = {0.f, 0.f, 0.f, 0.f};          // per-lane l partials
    f32x4 oacc[4] = {};                       // O^T: elem (d=dn*16+quad*4+r, q=lr)

    int ktmax = qt;
    {   // prologue: stage tile 0 into buffer 0 (2 K-rows + 2 V-rows / thread)
        s16x8 ka = *(const s16x8*)(kh + (size_t)srow * HD + sc8);
        s16x8 kb2 = *(const s16x8*)(kh + (size_t)(srow + 32) * HD + sc8);
        s16x8 va = *(const s16x8*)(vh + (size_t)srow * T_SEQ + sc8);
        s16x8 vb = *(const s16x8*)(vh + (size_t)(srow + 32) * T_SEQ + sc8);
        *(s16x8*)&Ks[0][srow * 64 + swsl] = ka;
        *(s16x8*)&Ks[0][(srow + 32) * 64 + swsl] = kb2;
        *(s16x8*)&Vs[0][srow * 64 + swsl] = va;
        *(s16x8*)&Vs[0][(srow + 32) * 64 + swsl] = vb;
    }
    __syncthreads();

    for (int kt = 0; kt <= ktmax; ++kt) {
        int cur = kt & 1;
        int k0 = kt * 64;
        bool pf = kt < ktmax;
        s16x8 kr0, kr1, vr0, vr1;             // next-tile prefetch registers
        if (pf) {
            int kn = k0 + 64;
            kr0 = *(const s16x8*)(kh + (size_t)(kn + srow) * HD + sc8);
            kr1 = *(const s16x8*)(kh + (size_t)(kn + srow + 32) * HD + sc8);
            vr0 = *(const s16x8*)(vh + (size_t)srow * T_SEQ + kn + sc8);
            vr1 = *(const s16x8*)(vh + (size_t)(srow + 32) * T_SEQ + kn + sc8);
        }
        const u16* Kc = Ks[cur];
        const u16* Vc = Vs[cur];

        // fragments (all strips active every tile in the 64-row form)
        s16x8 ak[2][4];                       // K frag (m=k-row=lr, k=d)
#pragma unroll
        for (int ks = 0; ks < 2; ++ks)
#pragma unroll
            for (int tc = 0; tc < 4; ++tc)
                ak[ks][tc] = *(const s16x8*)&Kc[(tc * 16 + lr) * 64 + (((ks * 4 + quad) << 3) ^ lrx8)];
        s16x4 av[4][4];                       // V^T frag (m=d=dn*16+lr, k=tc*16+quad*4+j)
#pragma unroll
        for (int dn = 0; dn < 4; ++dn) {
            const u16* vrow = &Vc[(dn * 16 + lr) * 64 + ((quad & 1) << 2)];
#pragma unroll
            for (int tc = 0; tc < 4; ++tc)
                av[dn][tc] = *(const s16x4*)(vrow + ((((tc << 1) + (quad >> 1)) << 3) ^ lrx8));
        }
        f32x4 sacc[4] = {};
        __builtin_amdgcn_s_setprio(1);        // T5: favor MFMA wave
#pragma unroll
        for (int ks = 0; ks < 2; ++ks)
#pragma unroll
            for (int tc = 0; tc < 4; ++tc) sacc[tc] = MFMA16(ak[ks][tc], aq[ks], sacc[tc]);
        __builtin_amdgcn_s_setprio(0);
        if (kt == ktmax) {                    // diagonal tile: causal mask
#pragma unroll
            for (int tc = 0; tc < 4; ++tc)
#pragma unroll
                for (int r = 0; r < 4; ++r)
                    if (k0 + tc * 16 + quad * 4 + r > rbase + lr) sacc[tc][r] = -1e30f;
        }
        // per-lane local max; __all == row-max guard
        f32x4 mv = sacc[0];
#pragma unroll
        for (int tc = 1; tc < 4; ++tc)
#pragma unroll
            for (int r = 0; r < 4; ++r) mv[r] = fmaxf(mv[r], sacc[tc][r]);
        float loc = fmaxf(fmaxf(mv[0], mv[1]), fmaxf(mv[2], mv[3]));
        bool need = !__all(loc <= m_i + 8.0f);   // defer-max (T13, THR=8)
        float alpha = 1.0f;
        if (need) {                            // rare: full cross-lane max
            float mx = fmaxf(loc, __shfl_xor(loc, 16, 64));
            mx = fmaxf(mx, __shfl_xor(mx, 32, 64));
            float mn = fmaxf(m_i, mx);
            alpha = __builtin_exp2f(m_i - mn);
            m_i = mn;
#pragma unroll
            for (int r = 0; r < 4; ++r) l4[r] *= alpha;
        }
        float mnow = m_i;
#pragma unroll
        for (int tc = 0; tc < 4; ++tc)
#pragma unroll
            for (int r = 0; r < 4; ++r) {
                float p = __builtin_exp2f(sacc[tc][r] - mnow);
                sacc[tc][r] = p;
                l4[r] += p;                    // per-lane partial; folded at end
            }
        // P in registers: pack4cvt(sacc[tc]) IS the 16x16x16 B-frag
        s16x4 pa[4];
#pragma unroll
        for (int tc = 0; tc < 4; ++tc) pa[tc] = pack4cvt_s(sacc[tc]);
        if (need) {
#pragma unroll
            for (int dn = 0; dn < 4; ++dn)
#pragma unroll
                for (int r = 0; r < 4; ++r) oacc[dn][r] *= alpha;
        }
        __builtin_amdgcn_s_setprio(1);        // T5: favor MFMA wave
#pragma unroll
        for (int dn = 0; dn < 4; ++dn)
#pragma unroll
            for (int tc = 0; tc < 4; ++tc)
                oacc[dn] = MFMA16K16(av[dn][tc], pa[tc], oacc[dn]);
        __builtin_amdgcn_s_setprio(0);

        if (pf) {                              // write prefetched tile to other buffer
            int nx = cur ^ 1;
            *(s16x8*)&Ks[nx][srow * 64 + swsl] = kr0;
            *(s16x8*)&Ks[nx][(srow + 32) * 64 + swsl] = kr1;
            *(s16x8*)&Vs[nx][srow * 64 + swsl] = vr0;
            *(s16x8*)&Vs[nx][(srow + 32) * 64 + swsl] = vr1;
        }
        __syncthreads();                       // single barrier per k-tile
    }
    // fold l partials: 4 per-lane + the 4 lanes of each row (xor 16, 32)
    float rs = (l4[0] + l4[1]) + (l4[2] + l4[3]);
    rs += __shfl_xor(rs, 16, 64);
    rs += __shfl_xor(rs, 32, 64);
    int b = bh >> 4, hh = bh & 15;
    {
        float inv = 1.f / rs;
        int t = rbase + lr;
        size_t base = ((size_t)b * T_SEQ + t) * C_EMB + hh * HD;
#pragma unroll
        for (int dn = 0; dn < 4; ++dn) {
            f32x4 vv;
#pragma unroll
            for (int r = 0; r < 4; ++r) vv[r] = oacc[dn][r] * inv;
            *(u16x4*)(yab + base + dn * 16 + quad * 4) = pack4(vv);
        }
    }
}

// ---------------- k3: output projection (64x64 tiles, BK=64, dbuf) ---------
// grid (16, 64): n0 = bx*64, m0 = by*64. 256 thr / 4 waves; wave (wr,wc)
// owns 32x32 (acc[2][2]). LDS 32KB -> 4 blocks/CU x 4 waves = 16 waves/CU.
// 16 K-iters: per iter 4 gload16/thread, 8 b128 frag reads, 8 MFMA/wave,
// vmcnt(4) + 2 barriers. 8-slot XOR swizzle (qkv-verified).
__global__ __launch_bounds__(256) void proj_k(const u16* __restrict__ ya, const u16* __restrict__ Wpb,
                                              const float* __restrict__ bias, float* __restrict__ out) {
    __shared__ u16 As[2][4096];               // [buf][64][64] linear (content swizzled)
    __shared__ u16 Bs[2][4096];
    int tid = threadIdx.x;
    int n0 = blockIdx.x * 64, m0 = blockIdx.y * 64;
    int w = tid >> 6, lane = tid & 63, lr = lane & 15, quad = lane >> 4;
    int wr = w >> 1, wc = w & 1;
    f32x4 acc[2][2] = {};
    int srow = tid >> 3;                                  // staging row 0..31 (+32 second chunk)
    int swc8 = (((tid & 7) ^ (srow & 7)) << 3);           // pre-swizzled src col (u16)
    int soff = tid * 8;                                   // linear LDS u16 offset
    int lrx = lr & 7;                                     // fragment-read XOR key

#define PRJ_STAGE(bufi, kc) do {                                                     \
        gload16(ya  + (size_t)(m0 + srow) * C_EMB + (kc) + swc8,      &As[bufi][soff]);        \
        gload16(ya  + (size_t)(m0 + 32 + srow) * C_EMB + (kc) + swc8, &As[bufi][2048 + soff]); \
        gload16(Wpb + (size_t)(n0 + srow) * C_EMB + (kc) + swc8,      &Bs[bufi][soff]);        \
        gload16(Wpb + (size_t)(n0 + 32 + srow) * C_EMB + (kc) + swc8, &Bs[bufi][2048 + soff]); \
    } while (0)

    PRJ_STAGE(0, 0);
#pragma unroll 2
    for (int kt = 0; kt < 16; ++kt) {
        int cur = kt & 1;
        if (kt < 15) {
            PRJ_STAGE(cur ^ 1, (kt + 1) * 64);
            asm volatile("s_waitcnt vmcnt(4)" ::: "memory");
        } else {
            asm volatile("s_waitcnt vmcnt(0)" ::: "memory");
        }
        __builtin_amdgcn_s_barrier();
        asm volatile("" ::: "memory");
#pragma unroll
        for (int ks = 0; ks < 64; ks += 32) {
            int slot = (ks >> 3) + quad;                   // 0..7
            int rc8 = ((slot ^ lrx) << 3);                 // swizzled read col (u16)
            s16x8 af[2], bf[2];
#pragma unroll
            for (int i = 0; i < 2; ++i)
                af[i] = *(const s16x8*)&As[cur][(wr * 32 + i * 16 + lr) * 64 + rc8];
#pragma unroll
            for (int j = 0; j < 2; ++j)
                bf[j] = *(const s16x8*)&Bs[cur][(wc * 32 + j * 16 + lr) * 64 + rc8];
#pragma unroll
            for (int i = 0; i < 2; ++i)
#pragma unroll
                for (int j = 0; j < 2; ++j) acc[i][j] = MFMA16(af[i], bf[j], acc[i][j]);
        }
        asm volatile("" ::: "memory");
        __builtin_amdgcn_s_barrier();
    }
#undef PRJ_STAGE

    float bv[2];
#pragma unroll
    for (int j = 0; j < 2; ++j) bv[j] = bias[n0 + wc * 32 + j * 16 + lr];
#pragma unroll
    for (int i = 0; i < 2; ++i)
#pragma unroll
        for (int r = 0; r < 4; ++r) {
            int m = m0 + wr * 32 + i * 16 + quad * 4 + r;
#pragma unroll
            for (int j = 0; j < 2; ++j)
                out[(size_t)m * C_EMB + n0 + wc * 32 + j * 16 + lr] = acc[i][j][r] + bv[j];
        }
}

extern "C" void kernel_launch(void* const* d_in, const int* in_sizes, int n_in,
                              void* d_out, int out_size, void* d_ws, size_t ws_size,
                              hipStream_t stream) {
    // Inputs resolved BY ELEMENT COUNT (unique): x 4194304, W_attn 3145728,
    // b_attn 3072, W_proj 1048576, b_proj 1024. All fp32.
    const float *x = nullptr, *Wa = nullptr, *ba = nullptr, *Wp = nullptr, *bp = nullptr;
    for (int i = 0; i < n_in; ++i) {
        switch (in_sizes[i]) {
            case 4194304: x  = (const float*)d_in[i]; break;
            case 3145728: Wa = (const float*)d_in[i]; break;
            case 3072:    ba = (const float*)d_in[i]; break;
            case 1048576: Wp = (const float*)d_in[i]; break;
            case 1024:    bp = (const float*)d_in[i]; break;
            default: break;
        }
    }
    float* out = (float*)d_out;

    char* ws = (char*)d_ws;
    u16* qb     = (u16*)(ws);                    //  0.. 8 MiB  bf16 [B,H,T,D] (q*0.125*log2e)
    u16* kb     = (u16*)(ws + 8388608);          //  8..16 MiB  bf16 [B,H,T,D]
    u16* vt     = (u16*)(ws + 16777216);         // 16..24 MiB  bf16 [B,H,D,T]
    u16* yab    = (u16*)(ws + 25165824);         // 24..32 MiB  bf16 [B,T,C]
    float2* tab = (float2*)(ws + 33554432);      // 32..32.5 MiB
    u16* xb     = (u16*)(ws + 35651584);         // 34..42 MiB  bf16 [4096,1024]
    u16* Wab    = (u16*)(ws + 44040192);         // 42..48 MiB  bf16 [3072,1024]
    u16* Wpb    = (u16*)(ws + 50331648);         // 48..50 MiB  bf16 [1024,1024]

    prep_k<<<4352, 256, 0, stream>>>(x, Wa, Wp, xb, Wab, Wpb, tab);
    qkv_rope_k<<<dim3(24, 32), 256, 0, stream>>>(xb, Wab, ba, tab, qb, kb, vt);
    flash_k<<<dim3(32, 32), 256, 0, stream>>>(qb, kb, vt, yab);
    proj_k<<<dim3(16, 64), 256, 0, stream>>>(yab, Wpb, bp, out);
}